// Round 4
// baseline (248.973 us; speedup 1.0000x reference)
//
#include <hip/hip_runtime.h>
#include <hip/hip_bf16.h>
#include <stdint.h>
#include <stddef.h>

#define DEV static __device__ __forceinline__

typedef __attribute__((ext_vector_type(8))) short short8;   // 8 bf16 (4 VGPRs) MFMA A/B frag
typedef __attribute__((ext_vector_type(4))) float floatx4;  // MFMA C/D frag

constexpr int Tn = 4096, Dn = 512;
constexpr int NC = 128, CTm = 32;   // scan: 128 chunks of 32 along T

union U8s { uint4 u4; unsigned short us[8]; };
union U4f { float4 f4; float f[4]; };
union U4s { uint2 u2; unsigned short us[4]; };

DEV float b2f(unsigned short u) {
  union { unsigned int i; float f; } c; c.i = ((unsigned int)u) << 16; return c.f;
}
DEV unsigned short f2b(float f) {  // RNE float->bf16
  union { float f; unsigned int u; } c; c.f = f;
  unsigned int r = c.u + 0x7fffu + ((c.u >> 16) & 1u);
  return (unsigned short)(r >> 16);
}
DEV float fast_tanh(float x) {     // robust at +/-inf: 1-2/(e^{2x}+1)
  float e = __expf(2.0f * x);
  return 1.0f - 2.0f / (e + 1.0f);
}

typedef __attribute__((address_space(1))) void GVOID;
typedef __attribute__((address_space(3))) void LVOID;
DEV void async16(const unsigned short* g, unsigned short* l) {
  __builtin_amdgcn_global_load_lds((GVOID*)g, (LVOID*)l, 16, 0, 0);
}

// ===== fused dispatch 1: scan pass 1 (per-chunk sums) + weight prep =========
// grid 704 x 256: [0,512) scan_partial ; [512,640) transposes ; [640,704) converts
__global__ void k_fuse1(const float* __restrict__ dec, float* __restrict__ part,
                        const float* __restrict__ Wh, const float* __restrict__ Wo,
                        const float* __restrict__ W1, const float* __restrict__ W2,
                        unsigned short* __restrict__ WhT, unsigned short* __restrict__ WoT,
                        unsigned short* __restrict__ W1b, unsigned short* __restrict__ W2b) {
  int blk = blockIdx.x;
  if (blk < 512) {          // ---- scan pass 1: per-chunk partial sums (fp32)
    int idx = blk * 256 + threadIdx.x;   // B*NC*(D/4) = 131072 threads
    int d4 = idx & 127;
    int c  = (idx >> 7) & (NC - 1);
    int b  = idx >> 14;
    const float* p = dec + ((size_t)b * Tn + (size_t)c * CTm) * Dn + d4 * 4;
    float s[4] = {0,0,0,0};
#pragma unroll 4
    for (int i = 0; i < CTm; ++i) {
      U4f v; v.f4 = *(const float4*)(p + (size_t)i * Dn);
#pragma unroll
      for (int j = 0; j < 4; ++j) s[j] += v.f[j];
    }
    float* o = part + ((size_t)(b * NC + c)) * Dn + d4 * 4;
#pragma unroll
    for (int j = 0; j < 4; ++j) o[j] = s[j];
  } else {
    int wb = blk - 512;     // 0..191
    if (wb < 128) {         // ---- transpose section: Wh->WhT, Wo->WoT
      const float* in = (wb < 64) ? Wh : Wo;
      unsigned short* out = (wb < 64) ? WhT : WoT;
      int lb = wb & 63;
      __shared__ float t[64][65];
      int n0 = (lb & 7) * 64, k0 = (lb >> 3) * 64;
#pragma unroll
      for (int l = 0; l < 16; ++l) {
        int lin = l * 256 + threadIdx.x;
        int r = lin >> 6, c = lin & 63;
        t[r][c] = in[(size_t)(k0 + r) * 512 + n0 + c];
      }
      __syncthreads();
#pragma unroll
      for (int l = 0; l < 16; ++l) {
        int lin = l * 256 + threadIdx.x;
        int r = lin >> 6, c = lin & 63;
        out[(size_t)(n0 + r) * 512 + k0 + c] = f2b(t[c][r]);
      }
    } else {                // ---- convert section: W1->W1b, W2->W2b
      const float* in = (wb < 160) ? W1 : W2;
      unsigned short* out = (wb < 160) ? W1b : W2b;
      int lb = (wb - 128) & 31;
      size_t base = ((size_t)lb * 256 + threadIdx.x) * 32;
#pragma unroll
      for (int l = 0; l < 8; ++l) {
        U4f v; v.f4 = *(const float4*)(in + base + l * 4);
        U4s o;
#pragma unroll
        for (int j = 0; j < 4; ++j) o.us[j] = f2b(v.f[j]);
        *(uint2*)(out + base + l * 4) = o.u2;
      }
    }
  }
}

// ===== full-width GEMM core: BM=128, BN=512 (all N), BK=32, 8 waves =========
// C[m][n] = epi(sum_k A[m][k]*BT[n][k]).  A,BT bf16, K = 512 fixed, N = 512.
// Each block owns COMPLETE output rows -> LN can fuse into the epilogue.
// LDS: dbuf A (2x8KB) + dbuf B (2x32KB) = 80KB.  Chunk-XOR swizzle (16B chunk
// c ^= row&3) applied both-sides: pre-swizzled global source into linear
// global_load_lds dest, same XOR on ds_read_b128.
// Pipeline: stage t+1 before computing t; s_waitcnt vmcnt(5) keeps the next
// tile's 5 per-thread loads in flight across the barrier (never 0 in loop).
// EPI 0: C = bf16(tanh(acc + bias[n]))
// EPI 2: C = bf16(acc)
// EPI 5: out = LayerNorm(tanh(spo[b][n] - acc) + dec) * gamma + beta  (fp32)
template<int EPI>
DEV void gemm_core(const unsigned short* __restrict__ A,
                   const unsigned short* __restrict__ BT,
                   unsigned short* __restrict__ C,
                   const float* __restrict__ bias,
                   const float* __restrict__ spo,
                   const float* __restrict__ dec,
                   const float* __restrict__ gamma,
                   const float* __restrict__ beta,
                   float* __restrict__ out,
                   int m0) {
  __shared__ alignas(16) unsigned short sA[2][128 * 32];
  __shared__ alignas(16) unsigned short sB[2][512 * 32];
  __shared__ float lnS[128][4];
  __shared__ float lnQ[128][4];
  const int tid  = threadIdx.x;
  const int lane = tid & 63;
  const int w    = tid >> 6;
  const int wr   = w >> 2;          // 0..1  (M half: 64 rows)
  const int wc   = w & 3;           // 0..3  (N quarter: 128 cols)
  const int rs   = lane & 15;
  const int quad = lane >> 4;

  floatx4 acc[4][8];
#pragma unroll
  for (int i = 0; i < 4; ++i)
#pragma unroll
    for (int j = 0; j < 8; ++j) acc[i][j] = (floatx4){0.f, 0.f, 0.f, 0.f};

  // stage one K-step: A 128x32 (512 chunks, 1/thread) + B 512x32 (2048, 4/thread)
  auto STAGE = [&](int kt, int buf) {
    {
      int r = tid >> 2, c = tid & 3;
      int kc = (c ^ (r & 3)) * 8;               // pre-swizzled source column
      async16(A + (size_t)(m0 + r) * 512 + kt + kc, &sA[buf][tid * 8]);
    }
#pragma unroll
    for (int l = 0; l < 4; ++l) {
      int ch = l * 512 + tid;
      int r = ch >> 2, c = ch & 3;
      int kc = (c ^ (r & 3)) * 8;
      async16(BT + (size_t)r * 512 + kt + kc, &sB[buf][ch * 8]);
    }
  };

  auto COMPUTE = [&](int buf) {
    __builtin_amdgcn_s_setprio(1);
    const int co = (quad ^ (rs & 3)) * 8;       // swizzled read chunk (elems)
    short8 bfr[8];
#pragma unroll
    for (int nj = 0; nj < 8; ++nj)
      bfr[nj] = *(const short8*)(&sB[buf][(wc * 128 + nj * 16 + rs) * 32 + co]);
#pragma unroll
    for (int mi = 0; mi < 4; ++mi) {
      short8 af = *(const short8*)(&sA[buf][(wr * 64 + mi * 16 + rs) * 32 + co]);
#pragma unroll
      for (int nj = 0; nj < 8; ++nj)
        acc[mi][nj] = __builtin_amdgcn_mfma_f32_16x16x32_bf16(af, bfr[nj], acc[mi][nj], 0, 0, 0);
    }
    __builtin_amdgcn_s_setprio(0);
  };

  STAGE(0, 0);
  for (int t = 0; t < 15; ++t) {
    STAGE((t + 1) * 32, (t + 1) & 1);
    // cur tile's 5 per-thread loads done; next tile's 5 stay in flight
    asm volatile("s_waitcnt vmcnt(5)\n\ts_barrier" ::: "memory");
    COMPUTE(t & 1);
    asm volatile("s_barrier" ::: "memory");
  }
  asm volatile("s_waitcnt vmcnt(0)\n\ts_barrier" ::: "memory");
  COMPUTE(1);

  // ---- epilogue.  C/D layout: col = lane&15, row = quad*4 + reg ----
  if constexpr (EPI == 0 || EPI == 2) {
#pragma unroll
    for (int nj = 0; nj < 8; ++nj) {
      const int colg = wc * 128 + nj * 16 + rs;
      float bb = (EPI == 0) ? bias[colg] : 0.f;
#pragma unroll
      for (int mi = 0; mi < 4; ++mi) {
#pragma unroll
        for (int r = 0; r < 4; ++r) {
          const int rowg = m0 + wr * 64 + mi * 16 + quad * 4 + r;
          float v = acc[mi][nj][r];
          if constexpr (EPI == 0) v = fast_tanh(v + bb);
          C[(size_t)rowg * 512 + colg] = f2b(v);
        }
      }
    }
  } else {  // EPI == 5: F = tanh(spo - acc); x = F + dec; out = LN(x)
    const int bidx = m0 >> 12;                  // batch (4096 rows each)
    float spv[8], gv[8], bv[8];
    int colv[8];
#pragma unroll
    for (int nj = 0; nj < 8; ++nj) {
      colv[nj] = wc * 128 + nj * 16 + rs;
      spv[nj] = spo[bidx * Dn + colv[nj]];
      gv[nj]  = gamma[colv[nj]];
      bv[nj]  = beta[colv[nj]];
    }
    // pass 1: overwrite acc with x = tanh(spo-acc)+dec, accumulate row partials
#pragma unroll
    for (int mi = 0; mi < 4; ++mi) {
#pragma unroll
      for (int r = 0; r < 4; ++r) {
        const int lrow = wr * 64 + mi * 16 + quad * 4 + r;
        const size_t rowg = (size_t)(m0 + lrow);
        float s = 0.f, sq = 0.f;
#pragma unroll
        for (int nj = 0; nj < 8; ++nj) {
          float dv = dec[rowg * 512 + colv[nj]];
          float xf = fast_tanh(spv[nj] - acc[mi][nj][r]) + dv;
          acc[mi][nj][r] = xf;
          s += xf; sq += xf * xf;
        }
#pragma unroll
        for (int o = 8; o > 0; o >>= 1) { s += __shfl_xor(s, o, 64); sq += __shfl_xor(sq, o, 64); }
        if (rs == 0) { lnS[lrow][wc] = s; lnQ[lrow][wc] = sq; }
      }
    }
    __syncthreads();
    // pass 2: combine 4 wc partials, normalize, store fp32
#pragma unroll
    for (int mi = 0; mi < 4; ++mi) {
#pragma unroll
      for (int r = 0; r < 4; ++r) {
        const int lrow = wr * 64 + mi * 16 + quad * 4 + r;
        const size_t rowg = (size_t)(m0 + lrow);
        float s = 0.f, sq = 0.f;
#pragma unroll
        for (int k = 0; k < 4; ++k) { s += lnS[lrow][k]; sq += lnQ[lrow][k]; }
        float mu   = s * (1.0f / 512.0f);
        float var  = sq * (1.0f / 512.0f) - mu * mu;
        float rstd = rsqrtf(var + 1e-6f);
#pragma unroll
        for (int nj = 0; nj < 8; ++nj)
          out[rowg * 512 + colv[nj]] = (acc[mi][nj][r] - mu) * rstd * gv[nj] + bv[nj];
      }
    }
  }
}

// GEMM1: H = tanh(M @ Wh + bh)
__global__ __launch_bounds__(512, 2)
void k_gemmH(const unsigned short* __restrict__ A, const unsigned short* __restrict__ BT,
             unsigned short* __restrict__ C, const float* __restrict__ bias) {
  gemm_core<0>(A, BT, C, bias, nullptr, nullptr, nullptr, nullptr, nullptr,
               blockIdx.x * 128);
}

// GEMM2 + fused residual/LayerNorm: out = LN(tanh(spo - H@W2Wo) + dec)
__global__ __launch_bounds__(512, 2)
void k_gemmFLN(const unsigned short* __restrict__ A, const unsigned short* __restrict__ BT,
               const float* __restrict__ spo, const float* __restrict__ dec,
               const float* __restrict__ gamma, const float* __restrict__ beta,
               float* __restrict__ out) {
  gemm_core<5>(A, BT, nullptr, nullptr, spo, dec, gamma, beta, out,
               blockIdx.x * 128);
}

// ===== fused dispatch 2: both weight GEMMs + part exclusive-scan ============
// grid 10 x 512: [0,4) W2@Wo tiles ; [4,8) W1@Wo tiles ; [8,10) part-scan
__global__ __launch_bounds__(512, 2)
void k_wgemm2(const unsigned short* __restrict__ WoT,
              const unsigned short* __restrict__ W2b, const unsigned short* __restrict__ W1b,
              unsigned short* __restrict__ W2WoT, unsigned short* __restrict__ W1WoT,
              float* __restrict__ part) {
  int blk = blockIdx.x;
  if (blk < 8) {
    const unsigned short* BT = (blk & 4) ? W1b : W2b;
    unsigned short* Cc = (blk & 4) ? W1WoT : W2WoT;
    gemm_core<2>(WoT, BT, Cc, nullptr, nullptr, nullptr, nullptr, nullptr, nullptr,
                 (blk & 3) * 128);
  } else {
    int idx = (blk - 8) * 512 + threadIdx.x;   // B*(D/4) = 1024 threads
    int d4 = idx & 127;
    int b  = idx >> 7;
    float* p = part + (size_t)b * NC * Dn + d4 * 4;
    float s[4] = {0, 0, 0, 0};
    for (int c0 = 0; c0 < NC; c0 += 8) {         // batch 8 loads in flight
      U4f v[8];
#pragma unroll
      for (int i = 0; i < 8; ++i) v[i].f4 = *(const float4*)(p + (size_t)(c0 + i) * Dn);
#pragma unroll
      for (int i = 0; i < 8; ++i) {
        U4f o;
#pragma unroll
        for (int j = 0; j < 4; ++j) { o.f[j] = s[j]; s[j] += v[i].f[j]; }
        *(float4*)(p + (size_t)(c0 + i) * Dn) = o.f4;
      }
    }
  }
}

// ===== fused dispatch 3: scan apply (running mean -> bf16 M) + svec =========
// grid 1536 x 256: [0,512) scan_apply ; [512,1536) spo = bo + summ . W1WoT
__global__ void k_fuse3(const float* __restrict__ dec, const float* __restrict__ part,
                        unsigned short* __restrict__ M,
                        const float* __restrict__ summ,
                        const unsigned short* __restrict__ W1WoT,
                        const float* __restrict__ bo, float* __restrict__ spo) {
  int blk = blockIdx.x;
  if (blk < 512) {          // ---- running mean from exclusive chunk-prefix
    int idx = blk * 256 + threadIdx.x;   // B*NC*(D/4) = 131072 threads
    int d4 = idx & 127;
    int c  = (idx >> 7) & (NC - 1);
    int b  = idx >> 14;
    size_t rbase = (size_t)b * Tn + (size_t)c * CTm;
    U4f s; s.f4 = *(const float4*)(part + ((size_t)b * NC + c) * Dn + d4 * 4);
    int t0 = c * CTm;
    const float* dp = dec + rbase * Dn + d4 * 4;
    unsigned short* mp = M + rbase * Dn + d4 * 4;
#pragma unroll 4
    for (int i = 0; i < CTm; ++i) {
      U4f v; v.f4 = *(const float4*)(dp + (size_t)i * Dn);
      float inv = 1.0f / (float)(t0 + i + 1);
      U4s o;
#pragma unroll
      for (int j = 0; j < 4; ++j) { s.f[j] += v.f[j]; o.us[j] = f2b(s.f[j] * inv); }
      *(uint2*)(mp + (size_t)i * Dn) = o.u2;
    }
  } else {                  // ---- spo[b][n] (wave per output)
    int widx = (blk - 512) * 4 + (threadIdx.x >> 6);   // 4096 waves
    int lane = threadIdx.x & 63;
    int n = widx & 511; int b = widx >> 9;
    U8s w8; w8.u4 = *(const uint4*)(W1WoT + (size_t)n * Dn + lane * 8);
    U4f s0, s1;
    s0.f4 = *(const float4*)(summ + (size_t)b * Dn + lane * 8);
    s1.f4 = *(const float4*)(summ + (size_t)b * Dn + lane * 8 + 4);
    float acc = 0.f;
#pragma unroll
    for (int j = 0; j < 4; ++j) acc += s0.f[j] * b2f(w8.us[j]);
#pragma unroll
    for (int j = 0; j < 4; ++j) acc += s1.f[j] * b2f(w8.us[j + 4]);
#pragma unroll
    for (int o = 32; o > 0; o >>= 1) acc += __shfl_xor(acc, o, 64);
    if (lane == 0) spo[(size_t)b * Dn + n] = acc + bo[n];
  }
}

extern "C" void kernel_launch(void* const* d_in, const int* in_sizes, int n_in,
                              void* d_out, int out_size, void* d_ws, size_t ws_size,
                              hipStream_t stream) {
  (void)in_sizes; (void)n_in; (void)out_size; (void)ws_size;
  const float* summ = (const float*)d_in[0];
  const float* dec  = (const float*)d_in[1];
  const float* Wh   = (const float*)d_in[2];
  const float* bh   = (const float*)d_in[3];
  const float* W1   = (const float*)d_in[4];
  const float* W2   = (const float*)d_in[5];
  const float* Wo   = (const float*)d_in[6];
  const float* bo   = (const float*)d_in[7];
  const float* gam  = (const float*)d_in[8];
  const float* bet  = (const float*)d_in[9];
  float* out = (float*)d_out;

  char* ws = (char*)d_ws;
  unsigned short* Mbuf  = (unsigned short*)(ws);                 // 32 MB bf16 M
  unsigned short* Hbuf  = (unsigned short*)(ws + 33554432);      // 32 MB bf16 H
  float*          part  = (float*)(ws + 67108864);               // 2 MB fp32 chunk sums
  float*          spo   = (float*)(ws + 69206016);               // 16 KB
  unsigned short* WhT   = (unsigned short*)(ws + 69238784);      // 512 KB bf16
  unsigned short* WoT   = (unsigned short*)(ws + 69763072);      // 512 KB bf16
  unsigned short* W2b   = (unsigned short*)(ws + 70287360);      // 512 KB bf16 (W2 row-major)
  unsigned short* W2WoT = (unsigned short*)(ws + 70811648);      // 512 KB bf16 (= (W2@Wo)^T)
  unsigned short* W1b   = (unsigned short*)(ws + 71335936);      // 512 KB bf16 (W1 row-major)
  unsigned short* W1WoT = (unsigned short*)(ws + 71860224);      // 512 KB bf16 (= (W1@Wo)^T)

  // 1: chunk sums for the scan + weight transposes/converts (independent work)
  k_fuse1<<<704, 256, 0, stream>>>(dec, part, Wh, Wo, W1, W2, WhT, WoT, W1b, W2b);

  // 2: both weight GEMMs (full-width core) + exclusive prefix scan over part
  k_wgemm2<<<10, 512, 0, stream>>>(WoT, W2b, W1b, W2WoT, W1WoT, part);

  // 3: causal running mean -> M (bf16) + spo[b][n]
  k_fuse3<<<1536, 256, 0, stream>>>(dec, part, Mbuf, summ, W1WoT, bo, spo);

  // 4: H = tanh(M @ Wh + bh)        (A-panel read once: full-width N)
  k_gemmH<<<256, 512, 0, stream>>>(Mbuf, WhT, Hbuf, bh);

  // 5: out = LayerNorm(tanh(spo - H@W2Wo) + dec)   (F never touches HBM)
  k_gemmFLN<<<256, 512, 0, stream>>>(Hbuf, W2WoT, spo, dec, gam, bet, out);
}

// Round 5
// 247.812 us; speedup vs baseline: 1.0047x; 1.0047x over previous
//
#include <hip/hip_runtime.h>
#include <hip/hip_bf16.h>
#include <stdint.h>
#include <stddef.h>

#define DEV static __device__ __forceinline__

typedef __attribute__((ext_vector_type(8))) short short8;   // 8 bf16 (4 VGPRs) MFMA A/B frag
typedef __attribute__((ext_vector_type(4))) float floatx4;  // MFMA C/D frag

constexpr int Tn = 4096, Dn = 512;
constexpr int NC = 128, CTm = 32;   // scan: 128 chunks of 32 along T

union U8s { uint4 u4; unsigned short us[8]; };
union U4f { float4 f4; float f[4]; };
union U4s { uint2 u2; unsigned short us[4]; };

DEV float b2f(unsigned short u) {
  union { unsigned int i; float f; } c; c.i = ((unsigned int)u) << 16; return c.f;
}
DEV unsigned short f2b(float f) {  // RNE float->bf16
  union { float f; unsigned int u; } c; c.f = f;
  unsigned int r = c.u + 0x7fffu + ((c.u >> 16) & 1u);
  return (unsigned short)(r >> 16);
}
DEV float fast_tanh(float x) {     // robust at +/-inf: 1-2/(e^{2x}+1)
  float e = __expf(2.0f * x);
  return 1.0f - 2.0f / (e + 1.0f);
}

typedef __attribute__((address_space(1))) void GVOID;
typedef __attribute__((address_space(3))) void LVOID;
DEV void async16(const unsigned short* g, unsigned short* l) {
  __builtin_amdgcn_global_load_lds((GVOID*)g, (LVOID*)l, 16, 0, 0);
}

// ===== fused dispatch 1: scan pass 1 (per-chunk sums) + weight prep =========
// grid 704 x 256: [0,512) scan_partial ; [512,640) transposes ; [640,704) converts
__global__ void k_fuse1(const float* __restrict__ dec, float* __restrict__ part,
                        const float* __restrict__ Wh, const float* __restrict__ Wo,
                        const float* __restrict__ W1, const float* __restrict__ W2,
                        unsigned short* __restrict__ WhT, unsigned short* __restrict__ WoT,
                        unsigned short* __restrict__ W1b, unsigned short* __restrict__ W2b) {
  int blk = blockIdx.x;
  if (blk < 512) {          // ---- scan pass 1: per-chunk partial sums (fp32)
    int idx = blk * 256 + threadIdx.x;   // B*NC*(D/4) = 131072 threads
    int d4 = idx & 127;
    int c  = (idx >> 7) & (NC - 1);
    int b  = idx >> 14;
    const float* p = dec + ((size_t)b * Tn + (size_t)c * CTm) * Dn + d4 * 4;
    float s[4] = {0,0,0,0};
#pragma unroll 4
    for (int i = 0; i < CTm; ++i) {
      U4f v; v.f4 = *(const float4*)(p + (size_t)i * Dn);
#pragma unroll
      for (int j = 0; j < 4; ++j) s[j] += v.f[j];
    }
    float* o = part + ((size_t)(b * NC + c)) * Dn + d4 * 4;
#pragma unroll
    for (int j = 0; j < 4; ++j) o[j] = s[j];
  } else {
    int wb = blk - 512;     // 0..191
    if (wb < 128) {         // ---- transpose section: Wh->WhT, Wo->WoT
      const float* in = (wb < 64) ? Wh : Wo;
      unsigned short* out = (wb < 64) ? WhT : WoT;
      int lb = wb & 63;
      __shared__ float t[64][65];
      int n0 = (lb & 7) * 64, k0 = (lb >> 3) * 64;
#pragma unroll
      for (int l = 0; l < 16; ++l) {
        int lin = l * 256 + threadIdx.x;
        int r = lin >> 6, c = lin & 63;
        t[r][c] = in[(size_t)(k0 + r) * 512 + n0 + c];
      }
      __syncthreads();
#pragma unroll
      for (int l = 0; l < 16; ++l) {
        int lin = l * 256 + threadIdx.x;
        int r = lin >> 6, c = lin & 63;
        out[(size_t)(n0 + r) * 512 + k0 + c] = f2b(t[c][r]);
      }
    } else {                // ---- convert section: W1->W1b, W2->W2b
      const float* in = (wb < 160) ? W1 : W2;
      unsigned short* out = (wb < 160) ? W1b : W2b;
      int lb = (wb - 128) & 31;
      size_t base = ((size_t)lb * 256 + threadIdx.x) * 32;
#pragma unroll
      for (int l = 0; l < 8; ++l) {
        U4f v; v.f4 = *(const float4*)(in + base + l * 4);
        U4s o;
#pragma unroll
        for (int j = 0; j < 4; ++j) o.us[j] = f2b(v.f[j]);
        *(uint2*)(out + base + l * 4) = o.u2;
      }
    }
  }
}

// ===== full-width GEMM core: BM=128, BN=512 (all N), BK=32, 8 waves =========
// C[m][n] = epi(sum_k A[m][k]*BT[n][k]).  A,BT bf16, K = 512 fixed, N = 512.
// Each block owns COMPLETE output rows -> LN can fuse into the epilogue.
// LDS: dbuf A (2x8KB) + dbuf B (2x32KB) = 80KB.
// Swizzle: LDS row = 64B (16 banks), so XOR chunk with (r>>1)&3 -> max 2-way
// bank aliasing (free).  Applied BOTH sides: pre-swizzled global source into
// linear global_load_lds dest, same XOR on ds_read_b128.
// Pipeline: stage t+1 before computing t; s_waitcnt vmcnt(5) keeps the next
// tile's 5 per-thread loads in flight across the barrier (never 0 in loop).
// NOTE: launch_bounds must be (512,1): acc[4][8] = 128 VGPRs; a 2-block bound
// caps VGPRs at 128 and spills the accumulator to scratch (round-4 regression).
// EPI 0: C = bf16(tanh(acc + bias[n]))
// EPI 2: C = bf16(acc)
// EPI 5: out = LayerNorm(tanh(spo[b][n] - acc) + dec) * gamma + beta  (fp32)
template<int EPI>
DEV void gemm_core(const unsigned short* __restrict__ A,
                   const unsigned short* __restrict__ BT,
                   unsigned short* __restrict__ C,
                   const float* __restrict__ bias,
                   const float* __restrict__ spo,
                   const float* __restrict__ dec,
                   const float* __restrict__ gamma,
                   const float* __restrict__ beta,
                   float* __restrict__ out,
                   int m0) {
  __shared__ alignas(16) unsigned short sA[2][128 * 32];
  __shared__ alignas(16) unsigned short sB[2][512 * 32];
  __shared__ float lnS[128][4];
  __shared__ float lnQ[128][4];
  const int tid  = threadIdx.x;
  const int lane = tid & 63;
  const int w    = tid >> 6;
  const int wr   = w >> 2;          // 0..1  (M half: 64 rows)
  const int wc   = w & 3;           // 0..3  (N quarter: 128 cols)
  const int rs   = lane & 15;
  const int quad = lane >> 4;

  floatx4 acc[4][8];
#pragma unroll
  for (int i = 0; i < 4; ++i)
#pragma unroll
    for (int j = 0; j < 8; ++j) acc[i][j] = (floatx4){0.f, 0.f, 0.f, 0.f};

  // stage one K-step: A 128x32 (512 chunks, 1/thread) + B 512x32 (2048, 4/thread)
  auto STAGE = [&](int kt, int buf) {
    {
      int r = tid >> 2, c = tid & 3;
      int kc = (c ^ ((r >> 1) & 3)) * 8;        // pre-swizzled source column
      async16(A + (size_t)(m0 + r) * 512 + kt + kc, &sA[buf][tid * 8]);
    }
#pragma unroll
    for (int l = 0; l < 4; ++l) {
      int ch = l * 512 + tid;
      int r = ch >> 2, c = ch & 3;
      int kc = (c ^ ((r >> 1) & 3)) * 8;
      async16(BT + (size_t)r * 512 + kt + kc, &sB[buf][ch * 8]);
    }
  };

  auto COMPUTE = [&](int buf) {
    __builtin_amdgcn_s_setprio(1);
    const int co = (quad ^ ((rs >> 1) & 3)) * 8;   // swizzled read chunk (elems)
    short8 bfr[8];
#pragma unroll
    for (int nj = 0; nj < 8; ++nj)
      bfr[nj] = *(const short8*)(&sB[buf][(wc * 128 + nj * 16 + rs) * 32 + co]);
#pragma unroll
    for (int mi = 0; mi < 4; ++mi) {
      short8 af = *(const short8*)(&sA[buf][(wr * 64 + mi * 16 + rs) * 32 + co]);
#pragma unroll
      for (int nj = 0; nj < 8; ++nj)
        acc[mi][nj] = __builtin_amdgcn_mfma_f32_16x16x32_bf16(af, bfr[nj], acc[mi][nj], 0, 0, 0);
    }
    __builtin_amdgcn_s_setprio(0);
  };

  STAGE(0, 0);
  for (int t = 0; t < 15; ++t) {
    STAGE((t + 1) * 32, (t + 1) & 1);
    // cur tile's 5 per-thread loads done; next tile's 5 stay in flight
    asm volatile("s_waitcnt vmcnt(5)\n\ts_barrier" ::: "memory");
    COMPUTE(t & 1);
    asm volatile("s_barrier" ::: "memory");
  }
  asm volatile("s_waitcnt vmcnt(0)\n\ts_barrier" ::: "memory");
  COMPUTE(1);

  // ---- epilogue.  C/D layout: col = lane&15, row = quad*4 + reg ----
  if constexpr (EPI == 0 || EPI == 2) {
#pragma unroll
    for (int nj = 0; nj < 8; ++nj) {
      const int colg = wc * 128 + nj * 16 + rs;
      float bb = (EPI == 0) ? bias[colg] : 0.f;
#pragma unroll
      for (int mi = 0; mi < 4; ++mi) {
#pragma unroll
        for (int r = 0; r < 4; ++r) {
          const int rowg = m0 + wr * 64 + mi * 16 + quad * 4 + r;
          float v = acc[mi][nj][r];
          if constexpr (EPI == 0) v = fast_tanh(v + bb);
          C[(size_t)rowg * 512 + colg] = f2b(v);
        }
      }
    }
  } else {  // EPI == 5: F = tanh(spo - acc); x = F + dec; out = LN(x)
    const int bidx = m0 >> 12;                  // batch (4096 rows each)
    float spv[8], gv[8], bv[8];
    int colv[8];
#pragma unroll
    for (int nj = 0; nj < 8; ++nj) {
      colv[nj] = wc * 128 + nj * 16 + rs;
      spv[nj] = spo[bidx * Dn + colv[nj]];
      gv[nj]  = gamma[colv[nj]];
      bv[nj]  = beta[colv[nj]];
    }
    // pass 1: overwrite acc with x = tanh(spo-acc)+dec, accumulate row partials
#pragma unroll
    for (int mi = 0; mi < 4; ++mi) {
#pragma unroll
      for (int r = 0; r < 4; ++r) {
        const int lrow = wr * 64 + mi * 16 + quad * 4 + r;
        const size_t rowg = (size_t)(m0 + lrow);
        float s = 0.f, sq = 0.f;
#pragma unroll
        for (int nj = 0; nj < 8; ++nj) {
          float dv = dec[rowg * 512 + colv[nj]];
          float xf = fast_tanh(spv[nj] - acc[mi][nj][r]) + dv;
          acc[mi][nj][r] = xf;
          s += xf; sq += xf * xf;
        }
#pragma unroll
        for (int o = 8; o > 0; o >>= 1) { s += __shfl_xor(s, o, 64); sq += __shfl_xor(sq, o, 64); }
        if (rs == 0) { lnS[lrow][wc] = s; lnQ[lrow][wc] = sq; }
      }
    }
    __syncthreads();
    // pass 2: combine 4 wc partials, normalize, store fp32
#pragma unroll
    for (int mi = 0; mi < 4; ++mi) {
#pragma unroll
      for (int r = 0; r < 4; ++r) {
        const int lrow = wr * 64 + mi * 16 + quad * 4 + r;
        const size_t rowg = (size_t)(m0 + lrow);
        float s = 0.f, sq = 0.f;
#pragma unroll
        for (int k = 0; k < 4; ++k) { s += lnS[lrow][k]; sq += lnQ[lrow][k]; }
        float mu   = s * (1.0f / 512.0f);
        float var  = sq * (1.0f / 512.0f) - mu * mu;
        float rstd = rsqrtf(var + 1e-6f);
#pragma unroll
        for (int nj = 0; nj < 8; ++nj)
          out[rowg * 512 + colv[nj]] = (acc[mi][nj][r] - mu) * rstd * gv[nj] + bv[nj];
      }
    }
  }
}

// GEMM1: H = tanh(M @ Wh + bh)
__global__ __launch_bounds__(512, 1)
void k_gemmH(const unsigned short* __restrict__ A, const unsigned short* __restrict__ BT,
             unsigned short* __restrict__ C, const float* __restrict__ bias) {
  gemm_core<0>(A, BT, C, bias, nullptr, nullptr, nullptr, nullptr, nullptr,
               blockIdx.x * 128);
}

// GEMM2 + fused residual/LayerNorm: out = LN(tanh(spo - H@W2Wo) + dec)
__global__ __launch_bounds__(512, 1)
void k_gemmFLN(const unsigned short* __restrict__ A, const unsigned short* __restrict__ BT,
               const float* __restrict__ spo, const float* __restrict__ dec,
               const float* __restrict__ gamma, const float* __restrict__ beta,
               float* __restrict__ out) {
  gemm_core<5>(A, BT, nullptr, nullptr, spo, dec, gamma, beta, out,
               blockIdx.x * 128);
}

// ===== fused dispatch 2: both weight GEMMs + part exclusive-scan ============
// grid 10 x 512: [0,4) W2@Wo tiles ; [4,8) W1@Wo tiles ; [8,10) part-scan
__global__ __launch_bounds__(512, 1)
void k_wgemm2(const unsigned short* __restrict__ WoT,
              const unsigned short* __restrict__ W2b, const unsigned short* __restrict__ W1b,
              unsigned short* __restrict__ W2WoT, unsigned short* __restrict__ W1WoT,
              float* __restrict__ part) {
  int blk = blockIdx.x;
  if (blk < 8) {
    const unsigned short* BT = (blk & 4) ? W1b : W2b;
    unsigned short* Cc = (blk & 4) ? W1WoT : W2WoT;
    gemm_core<2>(WoT, BT, Cc, nullptr, nullptr, nullptr, nullptr, nullptr, nullptr,
                 (blk & 3) * 128);
  } else {
    int idx = (blk - 8) * 512 + threadIdx.x;   // B*(D/4) = 1024 threads
    int d4 = idx & 127;
    int b  = idx >> 7;
    float* p = part + (size_t)b * NC * Dn + d4 * 4;
    float s[4] = {0, 0, 0, 0};
    for (int c0 = 0; c0 < NC; c0 += 8) {         // batch 8 loads in flight
      U4f v[8];
#pragma unroll
      for (int i = 0; i < 8; ++i) v[i].f4 = *(const float4*)(p + (size_t)(c0 + i) * Dn);
#pragma unroll
      for (int i = 0; i < 8; ++i) {
        U4f o;
#pragma unroll
        for (int j = 0; j < 4; ++j) { o.f[j] = s[j]; s[j] += v[i].f[j]; }
        *(float4*)(p + (size_t)(c0 + i) * Dn) = o.f4;
      }
    }
  }
}

// ===== fused dispatch 3: scan apply (running mean -> bf16 M) + svec =========
// grid 1536 x 256: [0,512) scan_apply ; [512,1536) spo = bo + summ . W1WoT
__global__ void k_fuse3(const float* __restrict__ dec, const float* __restrict__ part,
                        unsigned short* __restrict__ M,
                        const float* __restrict__ summ,
                        const unsigned short* __restrict__ W1WoT,
                        const float* __restrict__ bo, float* __restrict__ spo) {
  int blk = blockIdx.x;
  if (blk < 512) {          // ---- running mean from exclusive chunk-prefix
    int idx = blk * 256 + threadIdx.x;   // B*NC*(D/4) = 131072 threads
    int d4 = idx & 127;
    int c  = (idx >> 7) & (NC - 1);
    int b  = idx >> 14;
    size_t rbase = (size_t)b * Tn + (size_t)c * CTm;
    U4f s; s.f4 = *(const float4*)(part + ((size_t)b * NC + c) * Dn + d4 * 4);
    int t0 = c * CTm;
    const float* dp = dec + rbase * Dn + d4 * 4;
    unsigned short* mp = M + rbase * Dn + d4 * 4;
#pragma unroll 4
    for (int i = 0; i < CTm; ++i) {
      U4f v; v.f4 = *(const float4*)(dp + (size_t)i * Dn);
      float inv = 1.0f / (float)(t0 + i + 1);
      U4s o;
#pragma unroll
      for (int j = 0; j < 4; ++j) { s.f[j] += v.f[j]; o.us[j] = f2b(s.f[j] * inv); }
      *(uint2*)(mp + (size_t)i * Dn) = o.u2;
    }
  } else {                  // ---- spo[b][n] (wave per output)
    int widx = (blk - 512) * 4 + (threadIdx.x >> 6);   // 4096 waves
    int lane = threadIdx.x & 63;
    int n = widx & 511; int b = widx >> 9;
    U8s w8; w8.u4 = *(const uint4*)(W1WoT + (size_t)n * Dn + lane * 8);
    U4f s0, s1;
    s0.f4 = *(const float4*)(summ + (size_t)b * Dn + lane * 8);
    s1.f4 = *(const float4*)(summ + (size_t)b * Dn + lane * 8 + 4);
    float acc = 0.f;
#pragma unroll
    for (int j = 0; j < 4; ++j) acc += s0.f[j] * b2f(w8.us[j]);
#pragma unroll
    for (int j = 0; j < 4; ++j) acc += s1.f[j] * b2f(w8.us[j + 4]);
#pragma unroll
    for (int o = 32; o > 0; o >>= 1) acc += __shfl_xor(acc, o, 64);
    if (lane == 0) spo[(size_t)b * Dn + n] = acc + bo[n];
  }
}

extern "C" void kernel_launch(void* const* d_in, const int* in_sizes, int n_in,
                              void* d_out, int out_size, void* d_ws, size_t ws_size,
                              hipStream_t stream) {
  (void)in_sizes; (void)n_in; (void)out_size; (void)ws_size;
  const float* summ = (const float*)d_in[0];
  const float* dec  = (const float*)d_in[1];
  const float* Wh   = (const float*)d_in[2];
  const float* bh   = (const float*)d_in[3];
  const float* W1   = (const float*)d_in[4];
  const float* W2   = (const float*)d_in[5];
  const float* Wo   = (const float*)d_in[6];
  const float* bo   = (const float*)d_in[7];
  const float* gam  = (const float*)d_in[8];
  const float* bet  = (const float*)d_in[9];
  float* out = (float*)d_out;

  char* ws = (char*)d_ws;
  unsigned short* Mbuf  = (unsigned short*)(ws);                 // 32 MB bf16 M
  unsigned short* Hbuf  = (unsigned short*)(ws + 33554432);      // 32 MB bf16 H
  float*          part  = (float*)(ws + 67108864);               // 2 MB fp32 chunk sums
  float*          spo   = (float*)(ws + 69206016);               // 16 KB
  unsigned short* WhT   = (unsigned short*)(ws + 69238784);      // 512 KB bf16
  unsigned short* WoT   = (unsigned short*)(ws + 69763072);      // 512 KB bf16
  unsigned short* W2b   = (unsigned short*)(ws + 70287360);      // 512 KB bf16 (W2 row-major)
  unsigned short* W2WoT = (unsigned short*)(ws + 70811648);      // 512 KB bf16 (= (W2@Wo)^T)
  unsigned short* W1b   = (unsigned short*)(ws + 71335936);      // 512 KB bf16 (W1 row-major)
  unsigned short* W1WoT = (unsigned short*)(ws + 71860224);      // 512 KB bf16 (= (W1@Wo)^T)

  // 1: chunk sums for the scan + weight transposes/converts (independent work)
  k_fuse1<<<704, 256, 0, stream>>>(dec, part, Wh, Wo, W1, W2, WhT, WoT, W1b, W2b);

  // 2: both weight GEMMs (full-width core) + exclusive prefix scan over part
  k_wgemm2<<<10, 512, 0, stream>>>(WoT, W2b, W1b, W2WoT, W1WoT, part);

  // 3: causal running mean -> M (bf16) + spo[b][n]
  k_fuse3<<<1536, 256, 0, stream>>>(dec, part, Mbuf, summ, W1WoT, bo, spo);

  // 4: H = tanh(M @ Wh + bh)        (A-panel read once: full-width N)
  k_gemmH<<<256, 512, 0, stream>>>(Mbuf, WhT, Hbuf, bh);

  // 5: out = LayerNorm(tanh(spo - H@W2Wo) + dec)   (F never touches HBM)
  k_gemmFLN<<<256, 512, 0, stream>>>(Hbuf, W2WoT, spo, dec, gam, bet, out);
}

// Round 6
// 244.376 us; speedup vs baseline: 1.0188x; 1.0141x over previous
//
#include <hip/hip_runtime.h>
#include <hip/hip_bf16.h>
#include <stdint.h>
#include <stddef.h>

#define DEV static __device__ __forceinline__

typedef __attribute__((ext_vector_type(8))) short short8;   // 8 bf16 (4 VGPRs) MFMA A/B frag
typedef __attribute__((ext_vector_type(4))) float floatx4;  // MFMA C/D frag

constexpr int Tn = 4096, Dn = 512;
constexpr int NC = 128, CTm = 32;   // scan: 128 chunks of 32 along T

union U8s { uint4 u4; unsigned short us[8]; };
union U4f { float4 f4; float f[4]; };
union U4s { uint2 u2; unsigned short us[4]; };

DEV float b2f(unsigned short u) {
  union { unsigned int i; float f; } c; c.i = ((unsigned int)u) << 16; return c.f;
}
DEV unsigned short f2b(float f) {  // RNE float->bf16
  union { float f; unsigned int u; } c; c.f = f;
  unsigned int r = c.u + 0x7fffu + ((c.u >> 16) & 1u);
  return (unsigned short)(r >> 16);
}
DEV float fast_tanh(float x) {     // robust at +/-inf: 1-2/(e^{2x}+1)
  float e = __expf(2.0f * x);
  return 1.0f - 2.0f / (e + 1.0f);
}

typedef __attribute__((address_space(1))) void GVOID;
typedef __attribute__((address_space(3))) void LVOID;
DEV void async16(const unsigned short* g, unsigned short* l) {
  __builtin_amdgcn_global_load_lds((GVOID*)g, (LVOID*)l, 16, 0, 0);
}

// ===== fused dispatch 1: scan pass 1 (per-chunk sums) + weight prep =========
// grid 704 x 256: [0,512) scan_partial ; [512,640) transposes ; [640,704) converts
__global__ void k_fuse1(const float* __restrict__ dec, float* __restrict__ part,
                        const float* __restrict__ Wh, const float* __restrict__ Wo,
                        const float* __restrict__ W1, const float* __restrict__ W2,
                        unsigned short* __restrict__ WhT, unsigned short* __restrict__ WoT,
                        unsigned short* __restrict__ W1b, unsigned short* __restrict__ W2b) {
  int blk = blockIdx.x;
  if (blk < 512) {          // ---- scan pass 1: per-chunk partial sums (fp32)
    int idx = blk * 256 + threadIdx.x;   // B*NC*(D/4) = 131072 threads
    int d4 = idx & 127;
    int c  = (idx >> 7) & (NC - 1);
    int b  = idx >> 14;
    const float* p = dec + ((size_t)b * Tn + (size_t)c * CTm) * Dn + d4 * 4;
    float s[4] = {0,0,0,0};
#pragma unroll 4
    for (int i = 0; i < CTm; ++i) {
      U4f v; v.f4 = *(const float4*)(p + (size_t)i * Dn);
#pragma unroll
      for (int j = 0; j < 4; ++j) s[j] += v.f[j];
    }
    float* o = part + ((size_t)(b * NC + c)) * Dn + d4 * 4;
#pragma unroll
    for (int j = 0; j < 4; ++j) o[j] = s[j];
  } else {
    int wb = blk - 512;     // 0..191
    if (wb < 128) {         // ---- transpose section: Wh->WhT, Wo->WoT
      const float* in = (wb < 64) ? Wh : Wo;
      unsigned short* out = (wb < 64) ? WhT : WoT;
      int lb = wb & 63;
      __shared__ float t[64][65];
      int n0 = (lb & 7) * 64, k0 = (lb >> 3) * 64;
#pragma unroll
      for (int l = 0; l < 16; ++l) {
        int lin = l * 256 + threadIdx.x;
        int r = lin >> 6, c = lin & 63;
        t[r][c] = in[(size_t)(k0 + r) * 512 + n0 + c];
      }
      __syncthreads();
#pragma unroll
      for (int l = 0; l < 16; ++l) {
        int lin = l * 256 + threadIdx.x;
        int r = lin >> 6, c = lin & 63;
        out[(size_t)(n0 + r) * 512 + k0 + c] = f2b(t[c][r]);
      }
    } else {                // ---- convert section: W1->W1b, W2->W2b
      const float* in = (wb < 160) ? W1 : W2;
      unsigned short* out = (wb < 160) ? W1b : W2b;
      int lb = (wb - 128) & 31;
      size_t base = ((size_t)lb * 256 + threadIdx.x) * 32;
#pragma unroll
      for (int l = 0; l < 8; ++l) {
        U4f v; v.f4 = *(const float4*)(in + base + l * 4);
        U4s o;
#pragma unroll
        for (int j = 0; j < 4; ++j) o.us[j] = f2b(v.f[j]);
        *(uint2*)(out + base + l * 4) = o.u2;
      }
    }
  }
}

// ===== full-width GEMM core: BM=128, BN=512 (all N), BK=32, 8 waves =========
// C[m][n] = epi(sum_k A[m][k]*BT[n][k]).  A,BT bf16, K = 512 fixed, N = 512.
// Each block owns COMPLETE output rows -> LN can fuse into the epilogue.
// LDS: 3-RING A (3x8KB) + B (3x32KB) = 120KB.  2-deep prefetch: stage tile
// t+2 while computing t; s_waitcnt vmcnt(10) drains only tile t, leaving the
// 10 loads of t+1/t+2 in flight (round-5 post-mortem: 1-deep + BK=32 gave
// only ~600cyc issue->wait vs ~900cyc HBM latency -> per-step stall).
// Swizzle: LDS row = 64B (16 banks); XOR chunk with (r>>1)&3 -> max 2-way
// bank aliasing (free).  Applied BOTH sides (pre-swizzled global source into
// linear global_load_lds dest; same XOR on ds_read_b128).
// NOTE: launch_bounds must be (512,1): acc[4][8] = 128 VGPRs; a 2-block bound
// caps VGPRs at 128 and spills the accumulator to scratch (round-4 regression).
// EPI 0: C = bf16(tanh(acc + bias[n]))
// EPI 2: C = bf16(acc)
// EPI 5: out = LayerNorm(tanh(spo[b][n] - acc) + dec) * gamma + beta  (fp32)
template<int EPI>
DEV void gemm_core(const unsigned short* __restrict__ A,
                   const unsigned short* __restrict__ BT,
                   unsigned short* __restrict__ C,
                   const float* __restrict__ bias,
                   const float* __restrict__ spo,
                   const float* __restrict__ dec,
                   const float* __restrict__ gamma,
                   const float* __restrict__ beta,
                   float* __restrict__ out,
                   int m0) {
  __shared__ alignas(16) unsigned short sA[3][128 * 32];
  __shared__ alignas(16) unsigned short sB[3][512 * 32];
  __shared__ float lnS[128][4];
  __shared__ float lnQ[128][4];
  const int tid  = threadIdx.x;
  const int lane = tid & 63;
  const int w    = tid >> 6;
  const int wr   = w >> 2;          // 0..1  (M half: 64 rows)
  const int wc   = w & 3;           // 0..3  (N quarter: 128 cols)
  const int rs   = lane & 15;
  const int quad = lane >> 4;

  floatx4 acc[4][8];
#pragma unroll
  for (int i = 0; i < 4; ++i)
#pragma unroll
    for (int j = 0; j < 8; ++j) acc[i][j] = (floatx4){0.f, 0.f, 0.f, 0.f};

  // stage one K-step: A 128x32 (512 chunks, 1/thread) + B 512x32 (2048, 4/thread)
  auto STAGE = [&](int kt, int buf) {
    {
      int r = tid >> 2, c = tid & 3;
      int kc = (c ^ ((r >> 1) & 3)) * 8;        // pre-swizzled source column
      async16(A + (size_t)(m0 + r) * 512 + kt + kc, &sA[buf][tid * 8]);
    }
#pragma unroll
    for (int l = 0; l < 4; ++l) {
      int ch = l * 512 + tid;
      int r = ch >> 2, c = ch & 3;
      int kc = (c ^ ((r >> 1) & 3)) * 8;
      async16(BT + (size_t)r * 512 + kt + kc, &sB[buf][ch * 8]);
    }
  };

  auto COMPUTE = [&](int buf) {
    __builtin_amdgcn_s_setprio(1);
    const int co = (quad ^ ((rs >> 1) & 3)) * 8;   // swizzled read chunk (elems)
    short8 bfr[8];
#pragma unroll
    for (int nj = 0; nj < 8; ++nj)
      bfr[nj] = *(const short8*)(&sB[buf][(wc * 128 + nj * 16 + rs) * 32 + co]);
#pragma unroll
    for (int mi = 0; mi < 4; ++mi) {
      short8 af = *(const short8*)(&sA[buf][(wr * 64 + mi * 16 + rs) * 32 + co]);
#pragma unroll
      for (int nj = 0; nj < 8; ++nj)
        acc[mi][nj] = __builtin_amdgcn_mfma_f32_16x16x32_bf16(af, bfr[nj], acc[mi][nj], 0, 0, 0);
    }
    __builtin_amdgcn_s_setprio(0);
  };

  // 3-ring, 2-deep prefetch over 16 K-tiles
  STAGE(0, 0);
  STAGE(32, 1);
  for (int t = 0; t < 14; ++t) {
    STAGE((t + 2) * 32, (t + 2) % 3);
    // tile t's 5 loads done; tiles t+1,t+2 (10 loads) stay in flight
    asm volatile("s_waitcnt vmcnt(10)\n\ts_barrier" ::: "memory");
    COMPUTE(t % 3);
    asm volatile("s_barrier" ::: "memory");   // all waves done before re-stage
  }
  asm volatile("s_waitcnt vmcnt(5)\n\ts_barrier" ::: "memory");
  COMPUTE(14 % 3);
  asm volatile("s_barrier" ::: "memory");
  asm volatile("s_waitcnt vmcnt(0)\n\ts_barrier" ::: "memory");
  COMPUTE(15 % 3);

  // ---- epilogue.  C/D layout: col = lane&15, row = quad*4 + reg ----
  if constexpr (EPI == 0 || EPI == 2) {
#pragma unroll
    for (int nj = 0; nj < 8; ++nj) {
      const int colg = wc * 128 + nj * 16 + rs;
      float bb = (EPI == 0) ? bias[colg] : 0.f;
#pragma unroll
      for (int mi = 0; mi < 4; ++mi) {
#pragma unroll
        for (int r = 0; r < 4; ++r) {
          const int rowg = m0 + wr * 64 + mi * 16 + quad * 4 + r;
          float v = acc[mi][nj][r];
          if constexpr (EPI == 0) v = fast_tanh(v + bb);
          C[(size_t)rowg * 512 + colg] = f2b(v);
        }
      }
    }
  } else {  // EPI == 5: F = tanh(spo - acc); x = F + dec; out = LN(x)
    const int bidx = m0 >> 12;                  // batch (4096 rows each)
    float spv[8], gv[8], bv[8];
    int colv[8];
#pragma unroll
    for (int nj = 0; nj < 8; ++nj) {
      colv[nj] = wc * 128 + nj * 16 + rs;
      spv[nj] = spo[bidx * Dn + colv[nj]];
      gv[nj]  = gamma[colv[nj]];
      bv[nj]  = beta[colv[nj]];
    }
    // pass 1: overwrite acc with x = tanh(spo-acc)+dec, accumulate row partials
#pragma unroll
    for (int mi = 0; mi < 4; ++mi) {
#pragma unroll
      for (int r = 0; r < 4; ++r) {
        const int lrow = wr * 64 + mi * 16 + quad * 4 + r;
        const size_t rowg = (size_t)(m0 + lrow);
        float s = 0.f, sq = 0.f;
#pragma unroll
        for (int nj = 0; nj < 8; ++nj) {
          float dv = dec[rowg * 512 + colv[nj]];
          float xf = fast_tanh(spv[nj] - acc[mi][nj][r]) + dv;
          acc[mi][nj][r] = xf;
          s += xf; sq += xf * xf;
        }
#pragma unroll
        for (int o = 8; o > 0; o >>= 1) { s += __shfl_xor(s, o, 64); sq += __shfl_xor(sq, o, 64); }
        if (rs == 0) { lnS[lrow][wc] = s; lnQ[lrow][wc] = sq; }
      }
    }
    __syncthreads();
    // pass 2: combine 4 wc partials, normalize, store fp32
#pragma unroll
    for (int mi = 0; mi < 4; ++mi) {
#pragma unroll
      for (int r = 0; r < 4; ++r) {
        const int lrow = wr * 64 + mi * 16 + quad * 4 + r;
        const size_t rowg = (size_t)(m0 + lrow);
        float s = 0.f, sq = 0.f;
#pragma unroll
        for (int k = 0; k < 4; ++k) { s += lnS[lrow][k]; sq += lnQ[lrow][k]; }
        float mu   = s * (1.0f / 512.0f);
        float var  = sq * (1.0f / 512.0f) - mu * mu;
        float rstd = rsqrtf(var + 1e-6f);
#pragma unroll
        for (int nj = 0; nj < 8; ++nj)
          out[rowg * 512 + colv[nj]] = (acc[mi][nj][r] - mu) * rstd * gv[nj] + bv[nj];
      }
    }
  }
}

// GEMM1: H = tanh(M @ Wh + bh)
__global__ __launch_bounds__(512, 1)
void k_gemmH(const unsigned short* __restrict__ A, const unsigned short* __restrict__ BT,
             unsigned short* __restrict__ C, const float* __restrict__ bias) {
  gemm_core<0>(A, BT, C, bias, nullptr, nullptr, nullptr, nullptr, nullptr,
               blockIdx.x * 128);
}

// GEMM2 + fused residual/LayerNorm: out = LN(tanh(spo - H@W2Wo) + dec)
__global__ __launch_bounds__(512, 1)
void k_gemmFLN(const unsigned short* __restrict__ A, const unsigned short* __restrict__ BT,
               const float* __restrict__ spo, const float* __restrict__ dec,
               const float* __restrict__ gamma, const float* __restrict__ beta,
               float* __restrict__ out) {
  gemm_core<5>(A, BT, nullptr, nullptr, spo, dec, gamma, beta, out,
               blockIdx.x * 128);
}

// ===== fused dispatch 2: both weight GEMMs + part exclusive-scan ============
// grid 10 x 512: [0,4) W2@Wo tiles ; [4,8) W1@Wo tiles ; [8,10) part-scan
__global__ __launch_bounds__(512, 1)
void k_wgemm2(const unsigned short* __restrict__ WoT,
              const unsigned short* __restrict__ W2b, const unsigned short* __restrict__ W1b,
              unsigned short* __restrict__ W2WoT, unsigned short* __restrict__ W1WoT,
              float* __restrict__ part) {
  int blk = blockIdx.x;
  if (blk < 8) {
    const unsigned short* BT = (blk & 4) ? W1b : W2b;
    unsigned short* Cc = (blk & 4) ? W1WoT : W2WoT;
    gemm_core<2>(WoT, BT, Cc, nullptr, nullptr, nullptr, nullptr, nullptr, nullptr,
                 (blk & 3) * 128);
  } else {
    int idx = (blk - 8) * 512 + threadIdx.x;   // B*(D/4) = 1024 threads
    int d4 = idx & 127;
    int b  = idx >> 7;
    float* p = part + (size_t)b * NC * Dn + d4 * 4;
    float s[4] = {0, 0, 0, 0};
    for (int c0 = 0; c0 < NC; c0 += 8) {         // batch 8 loads in flight
      U4f v[8];
#pragma unroll
      for (int i = 0; i < 8; ++i) v[i].f4 = *(const float4*)(p + (size_t)(c0 + i) * Dn);
#pragma unroll
      for (int i = 0; i < 8; ++i) {
        U4f o;
#pragma unroll
        for (int j = 0; j < 4; ++j) { o.f[j] = s[j]; s[j] += v[i].f[j]; }
        *(float4*)(p + (size_t)(c0 + i) * Dn) = o.f4;
      }
    }
  }
}

// ===== fused dispatch 3: scan apply (running mean -> bf16 M) + svec =========
// grid 1536 x 256: [0,512) scan_apply ; [512,1536) spo = bo + summ . W1WoT
__global__ void k_fuse3(const float* __restrict__ dec, const float* __restrict__ part,
                        unsigned short* __restrict__ M,
                        const float* __restrict__ summ,
                        const unsigned short* __restrict__ W1WoT,
                        const float* __restrict__ bo, float* __restrict__ spo) {
  int blk = blockIdx.x;
  if (blk < 512) {          // ---- running mean from exclusive chunk-prefix
    int idx = blk * 256 + threadIdx.x;   // B*NC*(D/4) = 131072 threads
    int d4 = idx & 127;
    int c  = (idx >> 7) & (NC - 1);
    int b  = idx >> 14;
    size_t rbase = (size_t)b * Tn + (size_t)c * CTm;
    U4f s; s.f4 = *(const float4*)(part + ((size_t)b * NC + c) * Dn + d4 * 4);
    int t0 = c * CTm;
    const float* dp = dec + rbase * Dn + d4 * 4;
    unsigned short* mp = M + rbase * Dn + d4 * 4;
#pragma unroll 4
    for (int i = 0; i < CTm; ++i) {
      U4f v; v.f4 = *(const float4*)(dp + (size_t)i * Dn);
      float inv = 1.0f / (float)(t0 + i + 1);
      U4s o;
#pragma unroll
      for (int j = 0; j < 4; ++j) { s.f[j] += v.f[j]; o.us[j] = f2b(s.f[j] * inv); }
      *(uint2*)(mp + (size_t)i * Dn) = o.u2;
    }
  } else {                  // ---- spo[b][n] (wave per output)
    int widx = (blk - 512) * 4 + (threadIdx.x >> 6);   // 4096 waves
    int lane = threadIdx.x & 63;
    int n = widx & 511; int b = widx >> 9;
    U8s w8; w8.u4 = *(const uint4*)(W1WoT + (size_t)n * Dn + lane * 8);
    U4f s0, s1;
    s0.f4 = *(const float4*)(summ + (size_t)b * Dn + lane * 8);
    s1.f4 = *(const float4*)(summ + (size_t)b * Dn + lane * 8 + 4);
    float acc = 0.f;
#pragma unroll
    for (int j = 0; j < 4; ++j) acc += s0.f[j] * b2f(w8.us[j]);
#pragma unroll
    for (int j = 0; j < 4; ++j) acc += s1.f[j] * b2f(w8.us[j + 4]);
#pragma unroll
    for (int o = 32; o > 0; o >>= 1) acc += __shfl_xor(acc, o, 64);
    if (lane == 0) spo[(size_t)b * Dn + n] = acc + bo[n];
  }
}

extern "C" void kernel_launch(void* const* d_in, const int* in_sizes, int n_in,
                              void* d_out, int out_size, void* d_ws, size_t ws_size,
                              hipStream_t stream) {
  (void)in_sizes; (void)n_in; (void)out_size; (void)ws_size;
  const float* summ = (const float*)d_in[0];
  const float* dec  = (const float*)d_in[1];
  const float* Wh   = (const float*)d_in[2];
  const float* bh   = (const float*)d_in[3];
  const float* W1   = (const float*)d_in[4];
  const float* W2   = (const float*)d_in[5];
  const float* Wo   = (const float*)d_in[6];
  const float* bo   = (const float*)d_in[7];
  const float* gam  = (const float*)d_in[8];
  const float* bet  = (const float*)d_in[9];
  float* out = (float*)d_out;

  char* ws = (char*)d_ws;
  unsigned short* Mbuf  = (unsigned short*)(ws);                 // 32 MB bf16 M
  unsigned short* Hbuf  = (unsigned short*)(ws + 33554432);      // 32 MB bf16 H
  float*          part  = (float*)(ws + 67108864);               // 2 MB fp32 chunk sums
  float*          spo   = (float*)(ws + 69206016);               // 16 KB
  unsigned short* WhT   = (unsigned short*)(ws + 69238784);      // 512 KB bf16
  unsigned short* WoT   = (unsigned short*)(ws + 69763072);      // 512 KB bf16
  unsigned short* W2b   = (unsigned short*)(ws + 70287360);      // 512 KB bf16 (W2 row-major)
  unsigned short* W2WoT = (unsigned short*)(ws + 70811648);      // 512 KB bf16 (= (W2@Wo)^T)
  unsigned short* W1b   = (unsigned short*)(ws + 71335936);      // 512 KB bf16 (W1 row-major)
  unsigned short* W1WoT = (unsigned short*)(ws + 71860224);      // 512 KB bf16 (= (W1@Wo)^T)

  // 1: chunk sums for the scan + weight transposes/converts (independent work)
  k_fuse1<<<704, 256, 0, stream>>>(dec, part, Wh, Wo, W1, W2, WhT, WoT, W1b, W2b);

  // 2: both weight GEMMs (full-width core) + exclusive prefix scan over part
  k_wgemm2<<<10, 512, 0, stream>>>(WoT, W2b, W1b, W2WoT, W1WoT, part);

  // 3: causal running mean -> M (bf16) + spo[b][n]
  k_fuse3<<<1536, 256, 0, stream>>>(dec, part, Mbuf, summ, W1WoT, bo, spo);

  // 4: H = tanh(M @ Wh + bh)        (A-panel read once: full-width N)
  k_gemmH<<<256, 512, 0, stream>>>(Mbuf, WhT, Hbuf, bh);

  // 5: out = LayerNorm(tanh(spo - H@W2Wo) + dec)   (F never touches HBM)
  k_gemmFLN<<<256, 512, 0, stream>>>(Hbuf, W2WoT, spo, dec, gam, bet, out);
}

// Round 7
// 234.818 us; speedup vs baseline: 1.0603x; 1.0407x over previous
//
#include <hip/hip_runtime.h>
#include <hip/hip_bf16.h>
#include <stdint.h>
#include <stddef.h>

#define DEV static __device__ __forceinline__

typedef __attribute__((ext_vector_type(8))) short short8;   // 8 bf16 (4 VGPRs) MFMA A/B frag
typedef __attribute__((ext_vector_type(4))) float floatx4;  // MFMA C/D frag

constexpr int Tn = 4096, Dn = 512;
constexpr int NC = 128, CTm = 32;   // scan: 128 chunks of 32 along T

union U8s { uint4 u4; unsigned short us[8]; };
union U4f { float4 f4; float f[4]; };
union U4s { uint2 u2; unsigned short us[4]; };

DEV float b2f(unsigned short u) {
  union { unsigned int i; float f; } c; c.i = ((unsigned int)u) << 16; return c.f;
}
DEV unsigned short f2b(float f) {  // RNE float->bf16
  union { float f; unsigned int u; } c; c.f = f;
  unsigned int r = c.u + 0x7fffu + ((c.u >> 16) & 1u);
  return (unsigned short)(r >> 16);
}
DEV float fast_tanh(float x) {     // robust at +/-inf: 1-2/(e^{2x}+1)
  float e = __expf(2.0f * x);
  return 1.0f - 2.0f / (e + 1.0f);
}

typedef __attribute__((address_space(1))) void GVOID;
typedef __attribute__((address_space(3))) void LVOID;
DEV void async16(const unsigned short* g, unsigned short* l) {
  __builtin_amdgcn_global_load_lds((GVOID*)g, (LVOID*)l, 16, 0, 0);
}

// ===== fused dispatch 1: scan pass 1 (per-chunk sums) + weight prep =========
// grid 704 x 256: [0,512) scan_partial ; [512,640) transposes ; [640,704) converts
__global__ void k_fuse1(const float* __restrict__ dec, float* __restrict__ part,
                        const float* __restrict__ Wh, const float* __restrict__ Wo,
                        const float* __restrict__ W1, const float* __restrict__ W2,
                        unsigned short* __restrict__ WhT, unsigned short* __restrict__ WoT,
                        unsigned short* __restrict__ W1b, unsigned short* __restrict__ W2b) {
  int blk = blockIdx.x;
  if (blk < 512) {          // ---- scan pass 1: per-chunk partial sums (fp32)
    int idx = blk * 256 + threadIdx.x;   // B*NC*(D/4) = 131072 threads
    int d4 = idx & 127;
    int c  = (idx >> 7) & (NC - 1);
    int b  = idx >> 14;
    const float* p = dec + ((size_t)b * Tn + (size_t)c * CTm) * Dn + d4 * 4;
    float s[4] = {0,0,0,0};
#pragma unroll 4
    for (int i = 0; i < CTm; ++i) {
      U4f v; v.f4 = *(const float4*)(p + (size_t)i * Dn);
#pragma unroll
      for (int j = 0; j < 4; ++j) s[j] += v.f[j];
    }
    float* o = part + ((size_t)(b * NC + c)) * Dn + d4 * 4;
#pragma unroll
    for (int j = 0; j < 4; ++j) o[j] = s[j];
  } else {
    int wb = blk - 512;     // 0..191
    if (wb < 128) {         // ---- transpose section: Wh->WhT, Wo->WoT
      const float* in = (wb < 64) ? Wh : Wo;
      unsigned short* out = (wb < 64) ? WhT : WoT;
      int lb = wb & 63;
      __shared__ float t[64][65];
      int n0 = (lb & 7) * 64, k0 = (lb >> 3) * 64;
#pragma unroll
      for (int l = 0; l < 16; ++l) {
        int lin = l * 256 + threadIdx.x;
        int r = lin >> 6, c = lin & 63;
        t[r][c] = in[(size_t)(k0 + r) * 512 + n0 + c];
      }
      __syncthreads();
#pragma unroll
      for (int l = 0; l < 16; ++l) {
        int lin = l * 256 + threadIdx.x;
        int r = lin >> 6, c = lin & 63;
        out[(size_t)(n0 + r) * 512 + k0 + c] = f2b(t[c][r]);
      }
    } else {                // ---- convert section: W1->W1b, W2->W2b
      const float* in = (wb < 160) ? W1 : W2;
      unsigned short* out = (wb < 160) ? W1b : W2b;
      int lb = (wb - 128) & 31;
      size_t base = ((size_t)lb * 256 + threadIdx.x) * 32;
#pragma unroll
      for (int l = 0; l < 8; ++l) {
        U4f v; v.f4 = *(const float4*)(in + base + l * 4);
        U4s o;
#pragma unroll
        for (int j = 0; j < 4; ++j) o.us[j] = f2b(v.f[j]);
        *(uint2*)(out + base + l * 4) = o.u2;
      }
    }
  }
}

// ===== k_gemmH: R1-proven 128x128-tile MFMA GEMM, H = tanh(M @ Wh + bh) =====
// 256 thr, 32 KB LDS, simple drain loop -> ~3 blocks/CU; cross-block TLP
// hides the vmcnt(0)+barrier drain (m114).  C = bf16(tanh(acc + bias[n])).
__global__ __launch_bounds__(256, 2)
void k_gemmH(const unsigned short* __restrict__ A, const unsigned short* __restrict__ BT,
             unsigned short* __restrict__ C, const float* __restrict__ bias) {
  __shared__ alignas(16) unsigned short sA[128 * 64];
  __shared__ alignas(16) unsigned short sB[128 * 64];
  const int m0 = blockIdx.x * 128, n0 = blockIdx.y * 128;
  const int tid  = threadIdx.x;
  const int lane = tid & 63;
  const int w    = tid >> 6;
  const int wm   = (w >> 1) * 64;
  const int wn   = (w & 1) * 64;
  const int rs   = lane & 15;
  const int quad = lane >> 4;

  floatx4 acc[4][4];
#pragma unroll
  for (int i = 0; i < 4; ++i)
#pragma unroll
    for (int j = 0; j < 4; ++j) acc[i][j] = (floatx4){0.f, 0.f, 0.f, 0.f};

  for (int kt = 0; kt < 512; kt += 64) {
#pragma unroll
    for (int l = 0; l < 4; ++l) {
      int ch = l * 256 + tid;
      int r = ch >> 3, kc = ch & 7;
      async16(A  + (size_t)(m0 + r) * 512 + kt + kc * 8, sA + (size_t)ch * 8);
      async16(BT + (size_t)(n0 + r) * 512 + kt + kc * 8, sB + (size_t)ch * 8);
    }
    asm volatile("s_waitcnt vmcnt(0)" ::: "memory");
    __syncthreads();

#pragma unroll
    for (int kk = 0; kk < 2; ++kk) {
      const int kb = kk * 32 + quad * 8;
      short8 af[4], bfr[4];
#pragma unroll
      for (int i = 0; i < 4; ++i)
        af[i] = *(const short8*)(sA + (size_t)(wm + i * 16 + rs) * 64 + kb);
#pragma unroll
      for (int j = 0; j < 4; ++j)
        bfr[j] = *(const short8*)(sB + (size_t)(wn + j * 16 + rs) * 64 + kb);
#pragma unroll
      for (int i = 0; i < 4; ++i)
#pragma unroll
        for (int j = 0; j < 4; ++j)
          acc[i][j] = __builtin_amdgcn_mfma_f32_16x16x32_bf16(af[i], bfr[j], acc[i][j], 0, 0, 0);
    }
    __syncthreads();
  }

  // C/D layout: col = lane&15, row = quad*4 + reg
#pragma unroll
  for (int i = 0; i < 4; ++i) {
#pragma unroll
    for (int j = 0; j < 4; ++j) {
      const int colg = n0 + wn + j * 16 + rs;
#pragma unroll
      for (int r = 0; r < 4; ++r) {
        const int rowg = m0 + wm + i * 16 + quad * 4 + r;
        C[(size_t)rowg * 512 + colg] = f2b(fast_tanh(acc[i][j][r] + bias[colg]));
      }
    }
  }
}

// ===== 64-row full-width core: BM=64, BN=512, BK=32, 8 waves, 36 KB LDS =====
// C[m][n] = epi(sum_k A[m][k]*BT[n][k]).  Single-buffered drain loop; TLP
// from 2 blocks/CU (LDS 38 KB, VGPR <=128 via launch_bounds(512,4)).
// Swizzle: LDS row = 64B; XOR 16B-chunk with (r>>1)&3 -> max 2-way (free),
// applied both sides (pre-swizzled global source; same XOR on ds_read).
// EPI 2: C = bf16(acc)
// EPI 5: out = LayerNorm(tanh(spo[b][n] - acc) + dec) * gamma + beta  (fp32)
template<int EPI>
DEV void gemm64_core(const unsigned short* __restrict__ A,
                     const unsigned short* __restrict__ BT,
                     unsigned short* __restrict__ C,
                     const float* __restrict__ spo,
                     const float* __restrict__ dec,
                     const float* __restrict__ gamma,
                     const float* __restrict__ beta,
                     float* __restrict__ out,
                     int m0) {
  __shared__ alignas(16) unsigned short sA[64 * 32];    // 4 KB
  __shared__ alignas(16) unsigned short sB[512 * 32];   // 32 KB
  __shared__ float lnS[64][4];
  __shared__ float lnQ[64][4];
  const int tid  = threadIdx.x;
  const int lane = tid & 63;
  const int w    = tid >> 6;
  const int wr   = w >> 2;          // 0..1  (32-row half)
  const int wc   = w & 3;           // 0..3  (128-col quarter)
  const int rs   = lane & 15;
  const int quad = lane >> 4;

  floatx4 acc[2][8];
#pragma unroll
  for (int i = 0; i < 2; ++i)
#pragma unroll
    for (int j = 0; j < 8; ++j) acc[i][j] = (floatx4){0.f, 0.f, 0.f, 0.f};

  for (int t = 0; t < 16; ++t) {
    const int kt = t * 32;
    if (tid < 256) {                       // A: 64x32 = 256 16B chunks
      int r = tid >> 2, c = tid & 3;
      int kc = (c ^ ((r >> 1) & 3)) * 8;   // pre-swizzled source column
      async16(A + (size_t)(m0 + r) * 512 + kt + kc, &sA[tid * 8]);
    }
#pragma unroll
    for (int l = 0; l < 4; ++l) {          // B: 512x32 = 2048 chunks, 4/thread
      int ch = l * 512 + tid;
      int r = ch >> 2, c = ch & 3;
      int kc = (c ^ ((r >> 1) & 3)) * 8;
      async16(BT + (size_t)r * 512 + kt + kc, &sB[ch * 8]);
    }
    asm volatile("s_waitcnt vmcnt(0)" ::: "memory");
    __syncthreads();

    const int co = (quad ^ ((rs >> 1) & 3)) * 8;   // swizzled read chunk
    short8 af0 = *(const short8*)(&sA[(wr * 32 + rs) * 32 + co]);
    short8 af1 = *(const short8*)(&sA[(wr * 32 + 16 + rs) * 32 + co]);
#pragma unroll
    for (int nj = 0; nj < 8; ++nj) {
      short8 bf = *(const short8*)(&sB[(wc * 128 + nj * 16 + rs) * 32 + co]);
      acc[0][nj] = __builtin_amdgcn_mfma_f32_16x16x32_bf16(af0, bf, acc[0][nj], 0, 0, 0);
      acc[1][nj] = __builtin_amdgcn_mfma_f32_16x16x32_bf16(af1, bf, acc[1][nj], 0, 0, 0);
    }
    __syncthreads();
  }

  // ---- epilogue.  C/D layout: col = lane&15, row = quad*4 + reg ----
  if constexpr (EPI == 2) {
#pragma unroll
    for (int nj = 0; nj < 8; ++nj) {
      const int colg = wc * 128 + nj * 16 + rs;
#pragma unroll
      for (int mi = 0; mi < 2; ++mi) {
#pragma unroll
        for (int r = 0; r < 4; ++r) {
          const int rowg = m0 + wr * 32 + mi * 16 + quad * 4 + r;
          C[(size_t)rowg * 512 + colg] = f2b(acc[mi][nj][r]);
        }
      }
    }
  } else {  // EPI == 5: F = tanh(spo - acc); x = F + dec; out = LN(x)
    const int bidx = m0 >> 12;              // batch (4096 rows each)
    // pass 1: overwrite acc with x = tanh(spo-acc)+dec, accumulate partials
#pragma unroll
    for (int mi = 0; mi < 2; ++mi) {
#pragma unroll
      for (int r = 0; r < 4; ++r) {
        const int lrow = wr * 32 + mi * 16 + quad * 4 + r;
        const size_t rowg = (size_t)(m0 + lrow);
        float s = 0.f, sq = 0.f;
#pragma unroll
        for (int nj = 0; nj < 8; ++nj) {
          const int colg = wc * 128 + nj * 16 + rs;
          float sp = spo[bidx * Dn + colg];
          float dv = dec[rowg * 512 + colg];
          float xf = fast_tanh(sp - acc[mi][nj][r]) + dv;
          acc[mi][nj][r] = xf;
          s += xf; sq += xf * xf;
        }
#pragma unroll
        for (int o = 8; o > 0; o >>= 1) { s += __shfl_xor(s, o, 64); sq += __shfl_xor(sq, o, 64); }
        if (rs == 0) { lnS[lrow][wc] = s; lnQ[lrow][wc] = sq; }
      }
    }
    __syncthreads();
    // pass 2: combine 4 wc partials, normalize, store fp32
#pragma unroll
    for (int mi = 0; mi < 2; ++mi) {
#pragma unroll
      for (int r = 0; r < 4; ++r) {
        const int lrow = wr * 32 + mi * 16 + quad * 4 + r;
        const size_t rowg = (size_t)(m0 + lrow);
        float s = 0.f, sq = 0.f;
#pragma unroll
        for (int k = 0; k < 4; ++k) { s += lnS[lrow][k]; sq += lnQ[lrow][k]; }
        float mu   = s * (1.0f / 512.0f);
        float var  = sq * (1.0f / 512.0f) - mu * mu;
        float rstd = rsqrtf(var + 1e-6f);
#pragma unroll
        for (int nj = 0; nj < 8; ++nj) {
          const int colg = wc * 128 + nj * 16 + rs;
          out[rowg * 512 + colg] = (acc[mi][nj][r] - mu) * rstd * gamma[colg] + beta[colg];
        }
      }
    }
  }
}

// GEMM2 + fused residual/LayerNorm: out = LN(tanh(spo - H@W2Wo) + dec)
__global__ __launch_bounds__(512, 4)
void k_gemmFLN(const unsigned short* __restrict__ A, const unsigned short* __restrict__ BT,
               const float* __restrict__ spo, const float* __restrict__ dec,
               const float* __restrict__ gamma, const float* __restrict__ beta,
               float* __restrict__ out) {
  gemm64_core<5>(A, BT, nullptr, spo, dec, gamma, beta, out, blockIdx.x * 64);
}

// ===== fused dispatch 2: both weight GEMMs + part exclusive-scan ============
// grid 18 x 512: [0,8) W2@Wo m-tiles ; [8,16) W1@Wo m-tiles ; [16,18) scan
__global__ __launch_bounds__(512, 4)
void k_wgemm2(const unsigned short* __restrict__ WoT,
              const unsigned short* __restrict__ W2b, const unsigned short* __restrict__ W1b,
              unsigned short* __restrict__ W2WoT, unsigned short* __restrict__ W1WoT,
              float* __restrict__ part) {
  int blk = blockIdx.x;
  if (blk < 16) {
    const unsigned short* BT = (blk & 8) ? W1b : W2b;
    unsigned short* Cc = (blk & 8) ? W1WoT : W2WoT;
    gemm64_core<2>(WoT, BT, Cc, nullptr, nullptr, nullptr, nullptr, nullptr,
                   (blk & 7) * 64);
  } else {
    int idx = (blk - 16) * 512 + threadIdx.x;   // B*(D/4) = 1024 threads
    int d4 = idx & 127;
    int b  = idx >> 7;
    float* p = part + (size_t)b * NC * Dn + d4 * 4;
    float s[4] = {0, 0, 0, 0};
    for (int c0 = 0; c0 < NC; c0 += 8) {         // batch 8 loads in flight
      U4f v[8];
#pragma unroll
      for (int i = 0; i < 8; ++i) v[i].f4 = *(const float4*)(p + (size_t)(c0 + i) * Dn);
#pragma unroll
      for (int i = 0; i < 8; ++i) {
        U4f o;
#pragma unroll
        for (int j = 0; j < 4; ++j) { o.f[j] = s[j]; s[j] += v[i].f[j]; }
        *(float4*)(p + (size_t)(c0 + i) * Dn) = o.f4;
      }
    }
  }
}

// ===== fused dispatch 3: scan apply (running mean -> bf16 M) + svec =========
// grid 1536 x 256: [0,512) scan_apply ; [512,1536) spo = bo + summ . W1WoT
__global__ void k_fuse3(const float* __restrict__ dec, const float* __restrict__ part,
                        unsigned short* __restrict__ M,
                        const float* __restrict__ summ,
                        const unsigned short* __restrict__ W1WoT,
                        const float* __restrict__ bo, float* __restrict__ spo) {
  int blk = blockIdx.x;
  if (blk < 512) {          // ---- running mean from exclusive chunk-prefix
    int idx = blk * 256 + threadIdx.x;   // B*NC*(D/4) = 131072 threads
    int d4 = idx & 127;
    int c  = (idx >> 7) & (NC - 1);
    int b  = idx >> 14;
    size_t rbase = (size_t)b * Tn + (size_t)c * CTm;
    U4f s; s.f4 = *(const float4*)(part + ((size_t)b * NC + c) * Dn + d4 * 4);
    int t0 = c * CTm;
    const float* dp = dec + rbase * Dn + d4 * 4;
    unsigned short* mp = M + rbase * Dn + d4 * 4;
#pragma unroll 4
    for (int i = 0; i < CTm; ++i) {
      U4f v; v.f4 = *(const float4*)(dp + (size_t)i * Dn);
      float inv = 1.0f / (float)(t0 + i + 1);
      U4s o;
#pragma unroll
      for (int j = 0; j < 4; ++j) { s.f[j] += v.f[j]; o.us[j] = f2b(s.f[j] * inv); }
      *(uint2*)(mp + (size_t)i * Dn) = o.u2;
    }
  } else {                  // ---- spo[b][n] (wave per output)
    int widx = (blk - 512) * 4 + (threadIdx.x >> 6);   // 4096 waves
    int lane = threadIdx.x & 63;
    int n = widx & 511; int b = widx >> 9;
    U8s w8; w8.u4 = *(const uint4*)(W1WoT + (size_t)n * Dn + lane * 8);
    U4f s0, s1;
    s0.f4 = *(const float4*)(summ + (size_t)b * Dn + lane * 8);
    s1.f4 = *(const float4*)(summ + (size_t)b * Dn + lane * 8 + 4);
    float acc = 0.f;
#pragma unroll
    for (int j = 0; j < 4; ++j) acc += s0.f[j] * b2f(w8.us[j]);
#pragma unroll
    for (int j = 0; j < 4; ++j) acc += s1.f[j] * b2f(w8.us[j + 4]);
#pragma unroll
    for (int o = 32; o > 0; o >>= 1) acc += __shfl_xor(acc, o, 64);
    if (lane == 0) spo[(size_t)b * Dn + n] = acc + bo[n];
  }
}

extern "C" void kernel_launch(void* const* d_in, const int* in_sizes, int n_in,
                              void* d_out, int out_size, void* d_ws, size_t ws_size,
                              hipStream_t stream) {
  (void)in_sizes; (void)n_in; (void)out_size; (void)ws_size;
  const float* summ = (const float*)d_in[0];
  const float* dec  = (const float*)d_in[1];
  const float* Wh   = (const float*)d_in[2];
  const float* bh   = (const float*)d_in[3];
  const float* W1   = (const float*)d_in[4];
  const float* W2   = (const float*)d_in[5];
  const float* Wo   = (const float*)d_in[6];
  const float* bo   = (const float*)d_in[7];
  const float* gam  = (const float*)d_in[8];
  const float* bet  = (const float*)d_in[9];
  float* out = (float*)d_out;

  char* ws = (char*)d_ws;
  unsigned short* Mbuf  = (unsigned short*)(ws);                 // 32 MB bf16 M
  unsigned short* Hbuf  = (unsigned short*)(ws + 33554432);      // 32 MB bf16 H
  float*          part  = (float*)(ws + 67108864);               // 2 MB fp32 chunk sums
  float*          spo   = (float*)(ws + 69206016);               // 16 KB
  unsigned short* WhT   = (unsigned short*)(ws + 69238784);      // 512 KB bf16
  unsigned short* WoT   = (unsigned short*)(ws + 69763072);      // 512 KB bf16
  unsigned short* W2b   = (unsigned short*)(ws + 70287360);      // 512 KB bf16 (W2 row-major)
  unsigned short* W2WoT = (unsigned short*)(ws + 70811648);      // 512 KB bf16 (= (W2@Wo)^T)
  unsigned short* W1b   = (unsigned short*)(ws + 71335936);      // 512 KB bf16 (W1 row-major)
  unsigned short* W1WoT = (unsigned short*)(ws + 71860224);      // 512 KB bf16 (= (W1@Wo)^T)

  // 1: chunk sums for the scan + weight transposes/converts (independent work)
  k_fuse1<<<704, 256, 0, stream>>>(dec, part, Wh, Wo, W1, W2, WhT, WoT, W1b, W2b);

  // 2: both weight GEMMs (64-row core) + exclusive prefix scan over part
  k_wgemm2<<<18, 512, 0, stream>>>(WoT, W2b, W1b, W2WoT, W1WoT, part);

  // 3: causal running mean -> M (bf16) + spo[b][n]
  k_fuse3<<<1536, 256, 0, stream>>>(dec, part, Mbuf, summ, W1WoT, bo, spo);

  // 4: H = tanh(M @ Wh + bh)        (R1-proven 128x128 core, ~3 blocks/CU)
  k_gemmH<<<dim3(256, 4), 256, 0, stream>>>(Mbuf, WhT, Hbuf, bh);

  // 5: out = LayerNorm(tanh(spo - H@W2Wo) + dec)   (BM=64, 2 blocks/CU)
  k_gemmFLN<<<512, 512, 0, stream>>>(Hbuf, W2WoT, spo, dec, gam, bet, out);
}

// Round 8
// 231.532 us; speedup vs baseline: 1.0753x; 1.0142x over previous
//
#include <hip/hip_runtime.h>
#include <hip/hip_bf16.h>
#include <stdint.h>
#include <stddef.h>

#define DEV static __device__ __forceinline__

typedef __attribute__((ext_vector_type(8))) short short8;   // 8 bf16 (4 VGPRs) MFMA A/B frag
typedef __attribute__((ext_vector_type(4))) float floatx4;  // MFMA C/D frag

constexpr int Tn = 4096, Dn = 512;
constexpr int NC = 128, CTm = 32;   // scan: 128 chunks of 32 along T

union U8s { uint4 u4; unsigned short us[8]; };
union U4f { float4 f4; float f[4]; };
union U4s { uint2 u2; unsigned short us[4]; };

DEV float b2f(unsigned short u) {
  union { unsigned int i; float f; } c; c.i = ((unsigned int)u) << 16; return c.f;
}
DEV unsigned short f2b(float f) {  // RNE float->bf16
  union { float f; unsigned int u; } c; c.f = f;
  unsigned int r = c.u + 0x7fffu + ((c.u >> 16) & 1u);
  return (unsigned short)(r >> 16);
}
DEV float fast_tanh(float x) {     // robust at +/-inf: 1-2/(e^{2x}+1)
  float e = __expf(2.0f * x);
  return 1.0f - 2.0f / (e + 1.0f);
}

typedef __attribute__((address_space(1))) void GVOID;
typedef __attribute__((address_space(3))) void LVOID;
DEV void async16(const unsigned short* g, unsigned short* l) {
  __builtin_amdgcn_global_load_lds((GVOID*)g, (LVOID*)l, 16, 0, 0);
}

// ===== fused dispatch 1: scan pass 1 (per-chunk sums) + weight prep =========
// grid 704 x 256: [0,512) scan_partial ; [512,640) transposes ; [640,704) converts
__global__ void k_fuse1(const float* __restrict__ dec, float* __restrict__ part,
                        const float* __restrict__ Wh, const float* __restrict__ Wo,
                        const float* __restrict__ W1, const float* __restrict__ W2,
                        unsigned short* __restrict__ WhT, unsigned short* __restrict__ WoT,
                        unsigned short* __restrict__ W1b, unsigned short* __restrict__ W2b) {
  int blk = blockIdx.x;
  if (blk < 512) {          // ---- scan pass 1: per-chunk partial sums (fp32)
    int idx = blk * 256 + threadIdx.x;   // B*NC*(D/4) = 131072 threads
    int d4 = idx & 127;
    int c  = (idx >> 7) & (NC - 1);
    int b  = idx >> 14;
    const float* p = dec + ((size_t)b * Tn + (size_t)c * CTm) * Dn + d4 * 4;
    float s[4] = {0,0,0,0};
#pragma unroll 4
    for (int i = 0; i < CTm; ++i) {
      U4f v; v.f4 = *(const float4*)(p + (size_t)i * Dn);
#pragma unroll
      for (int j = 0; j < 4; ++j) s[j] += v.f[j];
    }
    float* o = part + ((size_t)(b * NC + c)) * Dn + d4 * 4;
#pragma unroll
    for (int j = 0; j < 4; ++j) o[j] = s[j];
  } else {
    int wb = blk - 512;     // 0..191
    if (wb < 128) {         // ---- transpose section: Wh->WhT, Wo->WoT
      const float* in = (wb < 64) ? Wh : Wo;
      unsigned short* out = (wb < 64) ? WhT : WoT;
      int lb = wb & 63;
      __shared__ float t[64][65];
      int n0 = (lb & 7) * 64, k0 = (lb >> 3) * 64;
#pragma unroll
      for (int l = 0; l < 16; ++l) {
        int lin = l * 256 + threadIdx.x;
        int r = lin >> 6, c = lin & 63;
        t[r][c] = in[(size_t)(k0 + r) * 512 + n0 + c];
      }
      __syncthreads();
#pragma unroll
      for (int l = 0; l < 16; ++l) {
        int lin = l * 256 + threadIdx.x;
        int r = lin >> 6, c = lin & 63;
        out[(size_t)(n0 + r) * 512 + k0 + c] = f2b(t[c][r]);
      }
    } else {                // ---- convert section: W1->W1b, W2->W2b
      const float* in = (wb < 160) ? W1 : W2;
      unsigned short* out = (wb < 160) ? W1b : W2b;
      int lb = (wb - 128) & 31;
      size_t base = ((size_t)lb * 256 + threadIdx.x) * 32;
#pragma unroll
      for (int l = 0; l < 8; ++l) {
        U4f v; v.f4 = *(const float4*)(in + base + l * 4);
        U4s o;
#pragma unroll
        for (int j = 0; j < 4; ++j) o.us[j] = f2b(v.f[j]);
        *(uint2*)(out + base + l * 4) = o.u2;
      }
    }
  }
}

// ===== full-width 128-row core: BM=128, BN=512, BK=32, 1024 thr / 16 waves ==
// C[m][n] = epi(sum_k A[m][k]*BT[n][k]).  A,BT bf16, K = 512 fixed, N = 512.
// Wave grid 4(M-bands of 32) x 4(N-bands of 128); acc[2][8] = 64 regs/thread
// -> fits the 128-VGPR cap a 1024-thread block implies.  LDS: dbuf A(2x8KB) +
// dbuf B(2x32KB) + ln(4KB) = 84KB -> 1 block/CU, one grid round (256 blocks).
// Counted-vmcnt pipeline: stage t+1 before computing t; waves 0-7 issue 3
// loads/step (A+2B), waves 8-15 issue 2 (2B) -> per-wave wait vmcnt(3)/(2)
// keeps next tile's loads in flight across the barrier (never 0 in loop).
// Swizzle: LDS row = 64B; XOR 16B-chunk with (r>>1)&3 -> max 2-way (free),
// both-sides (pre-swizzled global source; same XOR on ds_read_b128).
// EPI 0: C = bf16(tanh(acc + bias[n]))
// EPI 5: out = LayerNorm(tanh(spo[b][n] - acc) + dec) * gamma + beta  (fp32)
template<int EPI>
DEV void gemmFW_core(const unsigned short* __restrict__ A,
                     const unsigned short* __restrict__ BT,
                     unsigned short* __restrict__ C,
                     const float* __restrict__ bias,
                     const float* __restrict__ spo,
                     const float* __restrict__ dec,
                     const float* __restrict__ gamma,
                     const float* __restrict__ beta,
                     float* __restrict__ out,
                     int m0) {
  __shared__ alignas(16) unsigned short sA[2][128 * 32];   // 2 x 8 KB
  __shared__ alignas(16) unsigned short sB[2][512 * 32];   // 2 x 32 KB
  __shared__ float lnS[128][4];
  __shared__ float lnQ[128][4];
  const int tid  = threadIdx.x;
  const int lane = tid & 63;
  const int w    = tid >> 6;        // 0..15
  const int wr   = w >> 2;          // 0..3  (32-row band)
  const int wc   = w & 3;           // 0..3  (128-col band)
  const int rs   = lane & 15;
  const int quad = lane >> 4;

  floatx4 acc[2][8];
#pragma unroll
  for (int i = 0; i < 2; ++i)
#pragma unroll
    for (int j = 0; j < 8; ++j) acc[i][j] = (floatx4){0.f, 0.f, 0.f, 0.f};

  // stage one K-step: A 128x32 (512 chunks: tid<512, 1 each) + B 512x32 (2048: 2/thread)
  auto STAGE = [&](int kt, int buf) {
    if (tid < 512) {
      int r = tid >> 2, c = tid & 3;
      int kc = (c ^ ((r >> 1) & 3)) * 8;        // pre-swizzled source column
      async16(A + (size_t)(m0 + r) * 512 + kt + kc, &sA[buf][tid * 8]);
    }
#pragma unroll
    for (int l = 0; l < 2; ++l) {
      int ch = l * 1024 + tid;
      int r = ch >> 2, c = ch & 3;
      int kc = (c ^ ((r >> 1) & 3)) * 8;
      async16(BT + (size_t)r * 512 + kt + kc, &sB[buf][ch * 8]);
    }
  };

  auto COMPUTE = [&](int buf) {
    __builtin_amdgcn_s_setprio(1);
    const int co = (quad ^ ((rs >> 1) & 3)) * 8;   // swizzled read chunk
    short8 af0 = *(const short8*)(&sA[buf][(wr * 32 + rs) * 32 + co]);
    short8 af1 = *(const short8*)(&sA[buf][(wr * 32 + 16 + rs) * 32 + co]);
#pragma unroll
    for (int nj = 0; nj < 8; ++nj) {
      short8 bf = *(const short8*)(&sB[buf][(wc * 128 + nj * 16 + rs) * 32 + co]);
      acc[0][nj] = __builtin_amdgcn_mfma_f32_16x16x32_bf16(af0, bf, acc[0][nj], 0, 0, 0);
      acc[1][nj] = __builtin_amdgcn_mfma_f32_16x16x32_bf16(af1, bf, acc[1][nj], 0, 0, 0);
    }
    __builtin_amdgcn_s_setprio(0);
  };

  STAGE(0, 0);
  for (int t = 0; t < 15; ++t) {
    STAGE((t + 1) * 32, (t + 1) & 1);
    // wait for tile t's loads only; tile t+1's stay in flight across barrier.
    // wave-uniform branch; both paths hit exactly one s_barrier (counts match)
    if (w < 8) asm volatile("s_waitcnt vmcnt(3)\n\ts_barrier" ::: "memory");
    else       asm volatile("s_waitcnt vmcnt(2)\n\ts_barrier" ::: "memory");
    COMPUTE(t & 1);
    asm volatile("s_barrier" ::: "memory");   // done reading buf before restage
  }
  asm volatile("s_waitcnt vmcnt(0)\n\ts_barrier" ::: "memory");
  COMPUTE(1);

  // ---- epilogue.  C/D layout: col = lane&15, row = quad*4 + reg ----
  if constexpr (EPI == 0) {
#pragma unroll
    for (int nj = 0; nj < 8; ++nj) {
      const int colg = wc * 128 + nj * 16 + rs;
      float bb = bias[colg];
#pragma unroll
      for (int mi = 0; mi < 2; ++mi) {
#pragma unroll
        for (int r = 0; r < 4; ++r) {
          const int rowg = m0 + wr * 32 + mi * 16 + quad * 4 + r;
          C[(size_t)rowg * 512 + colg] = f2b(fast_tanh(acc[mi][nj][r] + bb));
        }
      }
    }
  } else {  // EPI == 5: F = tanh(spo - acc); x = F + dec; out = LN(x)
    const int bidx = m0 >> 12;              // batch (4096 rows each; 128|4096)
    // pass 1: overwrite acc with x = tanh(spo-acc)+dec, accumulate partials
#pragma unroll
    for (int mi = 0; mi < 2; ++mi) {
#pragma unroll
      for (int r = 0; r < 4; ++r) {
        const int lrow = wr * 32 + mi * 16 + quad * 4 + r;
        const size_t rowg = (size_t)(m0 + lrow);
        float s = 0.f, sq = 0.f;
#pragma unroll
        for (int nj = 0; nj < 8; ++nj) {
          const int colg = wc * 128 + nj * 16 + rs;
          float sp = spo[bidx * Dn + colg];
          float dv = dec[rowg * 512 + colg];
          float xf = fast_tanh(sp - acc[mi][nj][r]) + dv;
          acc[mi][nj][r] = xf;
          s += xf; sq += xf * xf;
        }
#pragma unroll
        for (int o = 8; o > 0; o >>= 1) { s += __shfl_xor(s, o, 64); sq += __shfl_xor(sq, o, 64); }
        if (rs == 0) { lnS[lrow][wc] = s; lnQ[lrow][wc] = sq; }
      }
    }
    __syncthreads();
    // pass 2: combine 4 wc partials, normalize, store fp32
#pragma unroll
    for (int mi = 0; mi < 2; ++mi) {
#pragma unroll
      for (int r = 0; r < 4; ++r) {
        const int lrow = wr * 32 + mi * 16 + quad * 4 + r;
        const size_t rowg = (size_t)(m0 + lrow);
        float s = 0.f, sq = 0.f;
#pragma unroll
        for (int k = 0; k < 4; ++k) { s += lnS[lrow][k]; sq += lnQ[lrow][k]; }
        float mu   = s * (1.0f / 512.0f);
        float var  = sq * (1.0f / 512.0f) - mu * mu;
        float rstd = rsqrtf(var + 1e-6f);
#pragma unroll
        for (int nj = 0; nj < 8; ++nj) {
          const int colg = wc * 128 + nj * 16 + rs;
          out[rowg * 512 + colg] = (acc[mi][nj][r] - mu) * rstd * gamma[colg] + beta[colg];
        }
      }
    }
  }
}

// GEMM1: H = tanh(M @ Wh + bh)   (grid 256, 1024 thr, 1 block/CU)
__global__ __launch_bounds__(1024)
void k_gemmH(const unsigned short* __restrict__ A, const unsigned short* __restrict__ BT,
             unsigned short* __restrict__ C, const float* __restrict__ bias) {
  gemmFW_core<0>(A, BT, C, bias, nullptr, nullptr, nullptr, nullptr, nullptr,
                 blockIdx.x * 128);
}

// GEMM2 + fused residual/LayerNorm: out = LN(tanh(spo - H@W2Wo) + dec)
__global__ __launch_bounds__(1024)
void k_gemmFLN(const unsigned short* __restrict__ A, const unsigned short* __restrict__ BT,
               const float* __restrict__ spo, const float* __restrict__ dec,
               const float* __restrict__ gamma, const float* __restrict__ beta,
               float* __restrict__ out) {
  gemmFW_core<5>(A, BT, nullptr, nullptr, spo, dec, gamma, beta, out,
                 blockIdx.x * 128);
}

// ===== 64-row full-width core (weight GEMMs only): C = bf16(acc) ===========
DEV void gemm64_core(const unsigned short* __restrict__ A,
                     const unsigned short* __restrict__ BT,
                     unsigned short* __restrict__ C, int m0) {
  __shared__ alignas(16) unsigned short sA[64 * 32];    // 4 KB
  __shared__ alignas(16) unsigned short sB[512 * 32];   // 32 KB
  const int tid  = threadIdx.x;
  const int lane = tid & 63;
  const int w    = tid >> 6;
  const int wr   = w >> 2;
  const int wc   = w & 3;
  const int rs   = lane & 15;
  const int quad = lane >> 4;

  floatx4 acc[2][8];
#pragma unroll
  for (int i = 0; i < 2; ++i)
#pragma unroll
    for (int j = 0; j < 8; ++j) acc[i][j] = (floatx4){0.f, 0.f, 0.f, 0.f};

  for (int t = 0; t < 16; ++t) {
    const int kt = t * 32;
    if (tid < 256) {
      int r = tid >> 2, c = tid & 3;
      int kc = (c ^ ((r >> 1) & 3)) * 8;
      async16(A + (size_t)(m0 + r) * 512 + kt + kc, &sA[tid * 8]);
    }
#pragma unroll
    for (int l = 0; l < 4; ++l) {
      int ch = l * 512 + tid;
      int r = ch >> 2, c = ch & 3;
      int kc = (c ^ ((r >> 1) & 3)) * 8;
      async16(BT + (size_t)r * 512 + kt + kc, &sB[ch * 8]);
    }
    asm volatile("s_waitcnt vmcnt(0)" ::: "memory");
    __syncthreads();

    const int co = (quad ^ ((rs >> 1) & 3)) * 8;
    short8 af0 = *(const short8*)(&sA[(wr * 32 + rs) * 32 + co]);
    short8 af1 = *(const short8*)(&sA[(wr * 32 + 16 + rs) * 32 + co]);
#pragma unroll
    for (int nj = 0; nj < 8; ++nj) {
      short8 bf = *(const short8*)(&sB[(wc * 128 + nj * 16 + rs) * 32 + co]);
      acc[0][nj] = __builtin_amdgcn_mfma_f32_16x16x32_bf16(af0, bf, acc[0][nj], 0, 0, 0);
      acc[1][nj] = __builtin_amdgcn_mfma_f32_16x16x32_bf16(af1, bf, acc[1][nj], 0, 0, 0);
    }
    __syncthreads();
  }

#pragma unroll
  for (int nj = 0; nj < 8; ++nj) {
    const int colg = wc * 128 + nj * 16 + rs;
#pragma unroll
    for (int mi = 0; mi < 2; ++mi) {
#pragma unroll
      for (int r = 0; r < 4; ++r) {
        const int rowg = m0 + wr * 32 + mi * 16 + quad * 4 + r;
        C[(size_t)rowg * 512 + colg] = f2b(acc[mi][nj][r]);
      }
    }
  }
}

// ===== fused dispatch 2: both weight GEMMs + part exclusive-scan ============
// grid 18 x 512: [0,8) W2@Wo m-tiles ; [8,16) W1@Wo m-tiles ; [16,18) scan
__global__ __launch_bounds__(512, 4)
void k_wgemm2(const unsigned short* __restrict__ WoT,
              const unsigned short* __restrict__ W2b, const unsigned short* __restrict__ W1b,
              unsigned short* __restrict__ W2WoT, unsigned short* __restrict__ W1WoT,
              float* __restrict__ part) {
  int blk = blockIdx.x;
  if (blk < 16) {
    const unsigned short* BT = (blk & 8) ? W1b : W2b;
    unsigned short* Cc = (blk & 8) ? W1WoT : W2WoT;
    gemm64_core(WoT, BT, Cc, (blk & 7) * 64);
  } else {
    int idx = (blk - 16) * 512 + threadIdx.x;   // B*(D/4) = 1024 threads
    int d4 = idx & 127;
    int b  = idx >> 7;
    float* p = part + (size_t)b * NC * Dn + d4 * 4;
    float s[4] = {0, 0, 0, 0};
    for (int c0 = 0; c0 < NC; c0 += 8) {         // batch 8 loads in flight
      U4f v[8];
#pragma unroll
      for (int i = 0; i < 8; ++i) v[i].f4 = *(const float4*)(p + (size_t)(c0 + i) * Dn);
#pragma unroll
      for (int i = 0; i < 8; ++i) {
        U4f o;
#pragma unroll
        for (int j = 0; j < 4; ++j) { o.f[j] = s[j]; s[j] += v[i].f[j]; }
        *(float4*)(p + (size_t)(c0 + i) * Dn) = o.f4;
      }
    }
  }
}

// ===== fused dispatch 3: scan apply (running mean -> bf16 M) + svec =========
// grid 1536 x 256: [0,512) scan_apply ; [512,1536) spo = bo + summ . W1WoT
__global__ void k_fuse3(const float* __restrict__ dec, const float* __restrict__ part,
                        unsigned short* __restrict__ M,
                        const float* __restrict__ summ,
                        const unsigned short* __restrict__ W1WoT,
                        const float* __restrict__ bo, float* __restrict__ spo) {
  int blk = blockIdx.x;
  if (blk < 512) {          // ---- running mean from exclusive chunk-prefix
    int idx = blk * 256 + threadIdx.x;   // B*NC*(D/4) = 131072 threads
    int d4 = idx & 127;
    int c  = (idx >> 7) & (NC - 1);
    int b  = idx >> 14;
    size_t rbase = (size_t)b * Tn + (size_t)c * CTm;
    U4f s; s.f4 = *(const float4*)(part + ((size_t)b * NC + c) * Dn + d4 * 4);
    int t0 = c * CTm;
    const float* dp = dec + rbase * Dn + d4 * 4;
    unsigned short* mp = M + rbase * Dn + d4 * 4;
#pragma unroll 4
    for (int i = 0; i < CTm; ++i) {
      U4f v; v.f4 = *(const float4*)(dp + (size_t)i * Dn);
      float inv = 1.0f / (float)(t0 + i + 1);
      U4s o;
#pragma unroll
      for (int j = 0; j < 4; ++j) { s.f[j] += v.f[j]; o.us[j] = f2b(s.f[j] * inv); }
      *(uint2*)(mp + (size_t)i * Dn) = o.u2;
    }
  } else {                  // ---- spo[b][n] (wave per output)
    int widx = (blk - 512) * 4 + (threadIdx.x >> 6);   // 4096 waves
    int lane = threadIdx.x & 63;
    int n = widx & 511; int b = widx >> 9;
    U8s w8; w8.u4 = *(const uint4*)(W1WoT + (size_t)n * Dn + lane * 8);
    U4f s0, s1;
    s0.f4 = *(const float4*)(summ + (size_t)b * Dn + lane * 8);
    s1.f4 = *(const float4*)(summ + (size_t)b * Dn + lane * 8 + 4);
    float acc = 0.f;
#pragma unroll
    for (int j = 0; j < 4; ++j) acc += s0.f[j] * b2f(w8.us[j]);
#pragma unroll
    for (int j = 0; j < 4; ++j) acc += s1.f[j] * b2f(w8.us[j + 4]);
#pragma unroll
    for (int o = 32; o > 0; o >>= 1) acc += __shfl_xor(acc, o, 64);
    if (lane == 0) spo[(size_t)b * Dn + n] = acc + bo[n];
  }
}

extern "C" void kernel_launch(void* const* d_in, const int* in_sizes, int n_in,
                              void* d_out, int out_size, void* d_ws, size_t ws_size,
                              hipStream_t stream) {
  (void)in_sizes; (void)n_in; (void)out_size; (void)ws_size;
  const float* summ = (const float*)d_in[0];
  const float* dec  = (const float*)d_in[1];
  const float* Wh   = (const float*)d_in[2];
  const float* bh   = (const float*)d_in[3];
  const float* W1   = (const float*)d_in[4];
  const float* W2   = (const float*)d_in[5];
  const float* Wo   = (const float*)d_in[6];
  const float* bo   = (const float*)d_in[7];
  const float* gam  = (const float*)d_in[8];
  const float* bet  = (const float*)d_in[9];
  float* out = (float*)d_out;

  char* ws = (char*)d_ws;
  unsigned short* Mbuf  = (unsigned short*)(ws);                 // 32 MB bf16 M
  unsigned short* Hbuf  = (unsigned short*)(ws + 33554432);      // 32 MB bf16 H
  float*          part  = (float*)(ws + 67108864);               // 2 MB fp32 chunk sums
  float*          spo   = (float*)(ws + 69206016);               // 16 KB
  unsigned short* WhT   = (unsigned short*)(ws + 69238784);      // 512 KB bf16
  unsigned short* WoT   = (unsigned short*)(ws + 69763072);      // 512 KB bf16
  unsigned short* W2b   = (unsigned short*)(ws + 70287360);      // 512 KB bf16 (W2 row-major)
  unsigned short* W2WoT = (unsigned short*)(ws + 70811648);      // 512 KB bf16 (= (W2@Wo)^T)
  unsigned short* W1b   = (unsigned short*)(ws + 71335936);      // 512 KB bf16 (W1 row-major)
  unsigned short* W1WoT = (unsigned short*)(ws + 71860224);      // 512 KB bf16 (= (W1@Wo)^T)

  // 1: chunk sums for the scan + weight transposes/converts (independent work)
  k_fuse1<<<704, 256, 0, stream>>>(dec, part, Wh, Wo, W1, W2, WhT, WoT, W1b, W2b);

  // 2: both weight GEMMs (64-row core) + exclusive prefix scan over part
  k_wgemm2<<<18, 512, 0, stream>>>(WoT, W2b, W1b, W2WoT, W1WoT, part);

  // 3: causal running mean -> M (bf16) + spo[b][n]
  k_fuse3<<<1536, 256, 0, stream>>>(dec, part, Mbuf, summ, W1WoT, bo, spo);

  // 4: H = tanh(M @ Wh + bh)        (128-row full-width core, 16 waves, dbuf)
  k_gemmH<<<256, 1024, 0, stream>>>(Mbuf, WhT, Hbuf, bh);

  // 5: out = LayerNorm(tanh(spo - H@W2Wo) + dec)   (same core, LN fused)
  k_gemmFLN<<<256, 1024, 0, stream>>>(Hbuf, W2WoT, spo, dec, gam, bet, out);
}